// Round 13
// baseline (549.152 us; speedup 1.0000x reference)
//
#include <hip/hip_runtime.h>
#include <math.h>

#define NN 20000
#define NPAD 20096          // padded rows for unguarded MFMA staging (157*128)
#define CC 256
#define HH 8
#define EE 160000
#define TE 320000
#define KVSTRIDE 768        // bytes per kv row: kr 256xbf16 (512B) + vr 256xfp8 (256B)
#define APAN ((size_t)NPAD*32)   // u16 elems per A-operand k-panel (xbf/hbf/A2)
#define BPAN 40960               // u16 elems per Wt5 k-panel (1280*32)
#define OPAN 8192                // u16 elems per Wto k-panel (256*32)

typedef unsigned short u16;
typedef unsigned char u8;
typedef __attribute__((ext_vector_type(8))) short bf16x8;
typedef __attribute__((ext_vector_type(4))) float f32x4;
typedef __attribute__((ext_vector_type(2))) float f32x2;

__device__ __forceinline__ float gelu_exact(float x){
    return 0.5f*x*(1.0f+erff(x*0.7071067811865476f));
}
__device__ __forceinline__ u16 f2bf(float f){
    unsigned u = __float_as_uint(f);
    unsigned r = (u + 0x7fffu + ((u >> 16) & 1u)) >> 16;
    return (u16)r;
}
__device__ __forceinline__ float bf2f(u16 s){
    return __uint_as_float(((unsigned)s) << 16);
}
__device__ __forceinline__ void dec8(uint4 u, float* f){
    f[0]=__uint_as_float(u.x<<16); f[1]=__uint_as_float(u.x&0xffff0000u);
    f[2]=__uint_as_float(u.y<<16); f[3]=__uint_as_float(u.y&0xffff0000u);
    f[4]=__uint_as_float(u.z<<16); f[5]=__uint_as_float(u.z&0xffff0000u);
    f[6]=__uint_as_float(u.w<<16); f[7]=__uint_as_float(u.w&0xffff0000u);
}
__device__ __forceinline__ void dec8_fp8(uint2 u, float* f){
    f32x2 a = __builtin_amdgcn_cvt_pk_f32_fp8(u.x, false);
    f32x2 b = __builtin_amdgcn_cvt_pk_f32_fp8(u.x, true);
    f32x2 c = __builtin_amdgcn_cvt_pk_f32_fp8(u.y, false);
    f32x2 d = __builtin_amdgcn_cvt_pk_f32_fp8(u.y, true);
    f[0]=a.x; f[1]=a.y; f[2]=b.x; f[3]=b.y;
    f[4]=c.x; f[5]=c.y; f[6]=d.x; f[7]=d.y;
}
__device__ __forceinline__ uint2 enc8_fp8(const float* f){
    int t0 = __builtin_amdgcn_cvt_pk_fp8_f32(f[0], f[1], 0, false);
    t0     = __builtin_amdgcn_cvt_pk_fp8_f32(f[2], f[3], t0, true);
    int t1 = __builtin_amdgcn_cvt_pk_fp8_f32(f[4], f[5], 0, false);
    t1     = __builtin_amdgcn_cvt_pk_fp8_f32(f[6], f[7], t1, true);
    uint2 r; r.x = (unsigned)t0; r.y = (unsigned)t1;
    return r;
}
__device__ __forceinline__ float dot8(const float* a, const float* b){
    return a[0]*b[0]+a[1]*b[1]+a[2]*b[2]+a[3]*b[3]
          +a[4]*b[4]+a[5]*b[5]+a[6]*b[6]+a[7]*b[7];
}
__device__ __forceinline__ void gload_lds16(const u16* gsrc, u16* lds_dst){
    __builtin_amdgcn_global_load_lds((const __attribute__((address_space(1))) unsigned int*)gsrc,
                                     (__attribute__((address_space(3))) unsigned int*)lds_dst,
                                     16, 0, 0);
}

// ======================= CSR build =======================
__global__ void hist_k(const int* __restrict__ ei0, const int* __restrict__ ei1,
                       int* __restrict__ cnt){
    int e = blockIdx.x*256 + threadIdx.x;
    if (e < TE){
        int dst = (e < EE) ? ei0[EE + e] : ei1[EE + (e - EE)];
        atomicAdd(&cnt[dst], 1);
    }
}
__global__ void scan_block_k(const int* __restrict__ cnt, int* __restrict__ incl,
                             int* __restrict__ bsum){
    __shared__ int tmp[256];
    int tid = threadIdx.x;
    int i = blockIdx.x*256 + tid;
    int v = (i < NN) ? cnt[i] : 0;
    tmp[tid] = v;
    __syncthreads();
    for (int d=1; d<256; d<<=1){
        int t = (tid>=d) ? tmp[tid-d] : 0;
        __syncthreads();
        tmp[tid] += t;
        __syncthreads();
    }
    if (i < NN) incl[i] = tmp[tid];
    if (tid == 255) bsum[blockIdx.x] = tmp[255];
}
__global__ void scan_bsum_k(int* bsum, int nb){
    __shared__ int tmp[128];
    int tid = threadIdx.x;
    int v = (tid < nb) ? bsum[tid] : 0;
    tmp[tid] = v;
    __syncthreads();
    for (int d=1; d<128; d<<=1){
        int t = (tid>=d) ? tmp[tid-d] : 0;
        __syncthreads();
        tmp[tid] += t;
        __syncthreads();
    }
    if (tid < nb) bsum[tid] = tmp[tid] - v;   // exclusive
}
__global__ void finalize_rowptr_k(const int* __restrict__ cnt, const int* __restrict__ incl,
                                  const int* __restrict__ bsum, int* __restrict__ row_ptr){
    int i = blockIdx.x*256 + threadIdx.x;
    if (i < NN) row_ptr[i] = incl[i] - cnt[i] + bsum[blockIdx.x];
    if (i == NN) row_ptr[NN] = TE;
}
// stores the final kv-row index rel*NN+src per CSR slot
__global__ void scatter_k(const int* __restrict__ ei0, const int* __restrict__ ei1,
                          const int* __restrict__ row_ptr, int* __restrict__ cursor,
                          int* __restrict__ epk){
    int e = blockIdx.x*256 + threadIdx.x;
    if (e < TE){
        int src, dst, rel;
        if (e < EE){ src = ei0[e]; dst = ei0[EE+e]; rel = 0; }
        else { int ee=e-EE; src = ei1[ee]; dst = ei1[EE+ee]; rel = 1; }
        int pos = atomicAdd(&cursor[dst], 1);
        epk[row_ptr[dst] + pos] = rel*NN + src;
    }
}

// ======================= weight prep =======================
// Wt5 in k-panel layout: [l][kpanel 0..7][n 0..1279][32k]
__global__ void build_w5_k(const float* __restrict__ kqv_w, const float* __restrict__ krel,
                           const float* __restrict__ vrel, u16* __restrict__ Wt){
    int idx = blockIdx.x*256 + threadIdx.x;        // 4*1280*256
    int k = idx & 255;
    int n = (idx >> 8) % 1280;
    int l = idx / (1280*256);
    const float* W = kqv_w + (size_t)l*196608;     // [256][768]
    float val;
    if (n < 256){
        val = W[k*768 + 256 + n];
    } else {
        int g = (n-256) >> 8;
        int r = g & 1, isv = g >> 1;
        int c = (n-256) & 255;
        int h = c >> 5, f = c & 31;
        const float* Rm = (isv ? vrel : krel) + ((size_t)l*2 + r)*8192 + h*1024; // [32][32]
        int base = isv ? 512 : 0;
        float a = 0.f;
        #pragma unroll 8
        for (int d=0; d<32; ++d)
            a += W[k*768 + base + h*32 + d] * Rm[d*32 + f];
        val = a;
    }
    Wt[(size_t)l*327680 + (size_t)(k>>5)*BPAN + n*32 + (k&31)] = f2bf(val);
}
// bias5 (pre-rel bias) + per-col scale (prel/sqrt(DH) folded into kr cols)
__global__ void build_bias5_k(const float* __restrict__ kqv_b, const float* __restrict__ krel,
                              const float* __restrict__ vrel, const float* __restrict__ prel,
                              float* __restrict__ bias5, float* __restrict__ sc5){
    int idx = blockIdx.x*256 + threadIdx.x;        // 4*1280
    if (idx >= 4*1280) return;
    int n = idx % 1280, l = idx / 1280;
    const float* B = kqv_b + l*768;
    float val, scl = 1.f;
    if (n < 256) val = B[256+n];
    else {
        int g = (n-256) >> 8;
        int r = g & 1, isv = g >> 1;
        int c = (n-256) & 255;
        int h = c >> 5, f = c & 31;
        const float* Rm = (isv ? vrel : krel) + ((size_t)l*2 + r)*8192 + h*1024;
        int base = isv ? 512 : 0;
        float a = 0.f;
        for (int d=0; d<32; ++d) a += B[base + h*32 + d] * Rm[d*32 + f];
        val = a;
        if (!isv) scl = prel[l*16 + r*8 + h] * 0.17677669529663687f;
    }
    bias5[idx] = val;
    sc5[idx] = scl;
}
// out_w [l][k][n] fp32 -> Wto k-panels [l][kpanel][n][32k] bf16
__global__ void build_wo_k(const float* __restrict__ out_w, u16* __restrict__ Wto){
    int idx = blockIdx.x*256 + threadIdx.x;        // 4*256*256
    int k = idx & 255;
    int n = (idx >> 8) & 255;
    int l = idx >> 16;
    Wto[(size_t)l*65536 + (size_t)(k>>5)*OPAN + n*32 + (k&31)] =
        f2bf(out_w[(size_t)l*65536 + k*256 + n]);
}
// x fp32 row-major -> xbf bf16 k-panels [kpanel][row][32k]
__global__ void cvt_x_k(const float* __restrict__ x, u16* __restrict__ xbf){
    int idx = blockIdx.x*256 + threadIdx.x;        // 640000 (8 elems each)
    int e = idx*8;
    int row = e >> 8, col = e & 255;
    const float4* xp = (const float4*)x;
    float4 a = xp[(size_t)idx*2], b = xp[(size_t)idx*2+1];
    uint4 o;
    o.x = (unsigned)f2bf(a.x) | ((unsigned)f2bf(a.y)<<16);
    o.y = (unsigned)f2bf(a.z) | ((unsigned)f2bf(a.w)<<16);
    o.z = (unsigned)f2bf(b.x) | ((unsigned)f2bf(b.y)<<16);
    o.w = (unsigned)f2bf(b.z) | ((unsigned)f2bf(b.w)<<16);
    *(uint4*)&xbf[(size_t)(col>>5)*APAN + (size_t)row*32 + (col&31)] = o;
}

// ======================= K1: 5-output MFMA GEMM (panel-staged) =======================
__global__ __launch_bounds__(256) void gemm5_k(const u16* __restrict__ A,
        const u16* __restrict__ Wt, const float* __restrict__ biasp,
        const float* __restrict__ sc5p,
        u16* __restrict__ qb, u8* __restrict__ kvb){
    __shared__ __align__(16) char smem[33792];   // max(As+Bs=16K, Cs=128*66*4)
    u16* As = (u16*)smem;                        // 4096 u16
    u16* Bs = (u16*)(smem + 8192);               // 4096 u16
    float* Cs = (float*)smem;                    // 128*66 (aliases As/Bs post-K-loop)
    int tid = threadIdx.x;
    int w = tid >> 6, lane = tid & 63;
    int col0 = blockIdx.x * 128;
    int row0 = blockIdx.y * 128;
    int wm = w & 1, wn = w >> 1;
    f32x4 acc[4][4];
    #pragma unroll
    for (int i=0;i<4;++i)
        #pragma unroll
        for (int j=0;j<4;++j) acc[i][j] = (f32x4){0.f,0.f,0.f,0.f};

    int lm = lane & 15, quad = lane >> 4;
    int kq0 = quad ^ (lm & 3);
    int aoff = (wm*64 + lm)*32 + kq0*8;
    int boff = (wn*64 + lm)*32 + kq0*8;

    for (int kk = 0; kk < 8; ++kk){
        #pragma unroll
        for (int it = 0; it < 2; ++it){
            int s = w*128 + it*64 + lane;      // 16B slot id (0..511)
            int row = s >> 2, q0 = s & 3;
            int kq = q0 ^ (row & 3);           // write-side swizzle via source addr
            gload_lds16(&A [(size_t)kk*APAN + (size_t)(row0+row)*32 + kq*8], &As[(size_t)(w*128 + it*64)*8]);
            gload_lds16(&Wt[(size_t)kk*BPAN + (size_t)(col0+row)*32 + kq*8], &Bs[(size_t)(w*128 + it*64)*8]);
        }
        __syncthreads();
        bf16x8 af[4], bfr[4];
        #pragma unroll
        for (int mi=0; mi<4; ++mi) af[mi]  = *(bf16x8*)&As[aoff + mi*512];
        #pragma unroll
        for (int ni=0; ni<4; ++ni) bfr[ni] = *(bf16x8*)&Bs[boff + ni*512];
        #pragma unroll
        for (int mi=0; mi<4; ++mi)
            #pragma unroll
            for (int ni=0; ni<4; ++ni)
                acc[mi][ni] = __builtin_amdgcn_mfma_f32_16x16x32_bf16(af[mi], bfr[ni], acc[mi][ni], 0,0,0);
        __syncthreads();    // last iteration also fences As/Bs before Cs aliasing
    }

    int bufi = col0 >> 8;   // 0:q 1:kr0 2:kr1 3:vr0 4:vr1 (uniform per block)
    int cbase = col0 & 255;
    float bvv[4], scv[4];
    #pragma unroll
    for (int ni=0; ni<4; ++ni){
        bvv[ni] = biasp[col0 + wn*64 + ni*16 + lm];
        scv[ni] = sc5p [col0 + wn*64 + ni*16 + lm];
    }

    int rowl_s = tid >> 3;              // 0..31
    int col8   = tid & 7;               // 0..7 (8 lcols each)
    int gcb    = (col8 >> 2)*64 + (col8 & 3)*8;

    #pragma unroll
    for (int p=0; p<2; ++p){
        if (p) __syncthreads();
        #pragma unroll
        for (int nj=0; nj<2; ++nj){
            int ni = p*2 + nj;
            int lcol = wn*32 + nj*16 + lm;
            #pragma unroll
            for (int mi=0; mi<4; ++mi){
                #pragma unroll
                for (int t=0; t<4; ++t){
                    int lr = wm*64 + mi*16 + quad*4 + t;
                    Cs[lr*66 + lcol] = (acc[mi][ni][t] + bvv[ni]) * scv[ni];
                }
            }
        }
        __syncthreads();
        int cw = cbase + gcb + p*32;
        #pragma unroll
        for (int it=0; it<4; ++it){
            int rl = rowl_s + it*32;
            int r = row0 + rl;
            if (r < NN){
                const float* src = &Cs[rl*66 + col8*8];
                float cf[8];
                *(float4*)&cf[0] = *(const float4*)&src[0];
                *(float4*)&cf[4] = *(const float4*)&src[4];
                if (bufi == 0){
                    uint4 o;
                    o.x = (unsigned)f2bf(cf[0]) | ((unsigned)f2bf(cf[1])<<16);
                    o.y = (unsigned)f2bf(cf[2]) | ((unsigned)f2bf(cf[3])<<16);
                    o.z = (unsigned)f2bf(cf[4]) | ((unsigned)f2bf(cf[5])<<16);
                    o.w = (unsigned)f2bf(cf[6]) | ((unsigned)f2bf(cf[7])<<16);
                    *(uint4*)&qb[(size_t)r*256 + cw] = o;
                } else if (bufi <= 2){
                    int rel = bufi - 1;
                    uint4 o;
                    o.x = (unsigned)f2bf(cf[0]) | ((unsigned)f2bf(cf[1])<<16);
                    o.y = (unsigned)f2bf(cf[2]) | ((unsigned)f2bf(cf[3])<<16);
                    o.z = (unsigned)f2bf(cf[4]) | ((unsigned)f2bf(cf[5])<<16);
                    o.w = (unsigned)f2bf(cf[6]) | ((unsigned)f2bf(cf[7])<<16);
                    *(uint4*)&kvb[(size_t)(rel*NN + r)*KVSTRIDE + cw*2] = o;
                } else {
                    int rel = bufi - 3;
                    uint2 o = enc8_fp8(cf);
                    *(uint2*)&kvb[(size_t)(rel*NN + r)*KVSTRIDE + 512 + cw] = o;
                }
            }
        }
    }
}

// ======================= K2: split-wave CSR attention, online softmax ==============
// A2 output now in k-panel layout (A operand of gemmOln/gemmO)
__global__ __launch_bounds__(256) void attn_k(const u16* __restrict__ qb,
        const u8* __restrict__ kvb,
        const int* __restrict__ row_ptr, const int* __restrict__ epk,
        u16* __restrict__ A2){
    int wv = threadIdx.x >> 6, lane = threadIdx.x & 63;
    int node = blockIdx.x*4 + wv;
    int l32 = lane & 31;
    int half = lane >> 5;
    int start = row_ptr[node], end = row_ptr[node+1];
    float qf[8];
    {
        uint4 qr = *(const uint4*)&qb[(size_t)node*256 + l32*8];
        dec8(qr, qf);
    }
    float m = -1e30f, s = 0.f;
    float acc[8] = {0.f,0.f,0.f,0.f,0.f,0.f,0.f,0.f};

    int i0 = start + half;
    uint4 k0={0,0,0,0}, k1={0,0,0,0};
    uint2 v0={0,0}, v1={0,0};
    if (i0 < end){
        const u8* row = &kvb[(size_t)epk[i0]*KVSTRIDE];
        k0 = *(const uint4*)(row + l32*16);
        v0 = *(const uint2*)(row + 512 + l32*8);
    }
    if (i0 + 2 < end){
        const u8* row = &kvb[(size_t)epk[i0+2]*KVSTRIDE];
        k1 = *(const uint4*)(row + l32*16);
        v1 = *(const uint2*)(row + 512 + l32*8);
    }
    int pk = (i0 + 4 < end) ? epk[i0+4] : 0;

    for (int i = i0; i < end; i += 2){
        uint4 kc = k0;
        uint2 vc = v0;
        k0 = k1; v0 = v1;
        if (i + 4 < end){                      // refill depth-2 slot
            const u8* row = &kvb[(size_t)pk*KVSTRIDE];
            k1 = *(const uint4*)(row + l32*16);
            v1 = *(const uint2*)(row + 512 + l32*8);
        }
        if (i + 6 < end) pk = epk[i+6];        // index 3 deep
        float kv[8];
        dec8(kc, kv);
        float p = dot8(qf, kv);
        p += __shfl_xor(p, 1);
        p += __shfl_xor(p, 2);                 // logit (prel/sqrt folded into kr)
        float mo = m;
        m = fmaxf(m, p);
        float sc = __expf(mo - m);
        float pe = __expf(p - m);
        s = s*sc + pe;
        float vv[8];
        dec8_fp8(vc, vv);
        #pragma unroll
        for (int j=0;j<8;++j) acc[j] = acc[j]*sc + pe*vv[j];
    }
    // merge the two halves' online-softmax states (m=-1e30: no inf-inf NaN)
    float mO = __shfl_xor(m, 32);
    float mA = fmaxf(m, mO);
    float eS = __expf(m - mA);
    float sh = s * eS;
    float sA = sh + __shfl_xor(sh, 32);
    float rs = 1.f / fmaxf(sA, 1e-16f);
    float oA[8];
    #pragma unroll
    for (int j=0;j<8;++j){
        float a = acc[j] * eS;
        oA[j] = a + __shfl_xor(a, 32);
    }
    if (half == 0){
        u16 o[8];
        #pragma unroll
        for (int j=0;j<8;++j) o[j] = f2bf(gelu_exact(oA[j]*rs));
        uint4 ov;
        ov.x = (unsigned)o[0] | ((unsigned)o[1]<<16);
        ov.y = (unsigned)o[2] | ((unsigned)o[3]<<16);
        ov.z = (unsigned)o[4] | ((unsigned)o[5]<<16);
        ov.w = (unsigned)o[6] | ((unsigned)o[7]<<16);
        int c0 = l32*8;
        *(uint4*)&A2[(size_t)(c0>>5)*APAN + (size_t)node*32 + (c0&31)] = ov;
    }
}

// ======================= K3a: out GEMM + skip + relu + LN (layers 0-2) ===========
// A2 and Wto in k-panel layout -> contiguous staging runs.
// emits h_out fp32 (row-major) and hbf bf16 k-panels for next gemm5
__global__ __launch_bounds__(256) void gemmOln_k(const u16* __restrict__ A,
        const u16* __restrict__ Wt, const float* __restrict__ bias,
        const float* __restrict__ h_in, const float* __restrict__ skip_l,
        const float* __restrict__ g, const float* __restrict__ b,
        float* __restrict__ h_out, u16* __restrict__ hbf){
    __shared__ u16 As[2048];          // 64 rows x 32 k
    __shared__ u16 Bs[8192];          // 256 cols x 32 k
    __shared__ float part_s[64*33];
    __shared__ float part_q[64*33];
    __shared__ float mu_s[64], rstd_s[64];
    int tid = threadIdx.x;
    int w = tid >> 6, lane = tid & 63;
    int row0 = blockIdx.x * 64;
    int wm = w & 1, wn = w >> 1;
    f32x4 acc[2][8];
    #pragma unroll
    for (int i=0;i<2;++i)
        #pragma unroll
        for (int j=0;j<8;++j) acc[i][j] = (f32x4){0.f,0.f,0.f,0.f};

    int lm = lane & 15, quad = lane >> 4;
    int kq0 = quad ^ (lm & 3);
    int aoff = (wm*32 + lm)*32 + kq0*8;
    int boff = (wn*128 + lm)*32 + kq0*8;

    for (int kk = 0; kk < 8; ++kk){
        {
            int s = tid;                       // 256 slots = 64 rows x 4
            int row = s >> 2, q0 = s & 3;
            int kq = q0 ^ (row & 3);
            gload_lds16(&A[(size_t)kk*APAN + (size_t)(row0+row)*32 + kq*8], &As[(size_t)(w*64)*8]);
        }
        #pragma unroll
        for (int it = 0; it < 4; ++it){        // 1024 slots = 256 n-rows x 4
            int s = it*256 + w*64 + lane;
            int row = s >> 2, q0 = s & 3;
            int kq = q0 ^ (row & 3);
            gload_lds16(&Wt[(size_t)kk*OPAN + (size_t)row*32 + kq*8], &Bs[(size_t)(it*256 + w*64)*8]);
        }
        __syncthreads();
        bf16x8 af[2], bfr[8];
        #pragma unroll
        for (int mi=0; mi<2; ++mi) af[mi]  = *(bf16x8*)&As[aoff + mi*512];
        #pragma unroll
        for (int ni=0; ni<8; ++ni) bfr[ni] = *(bf16x8*)&Bs[boff + ni*512];
        #pragma unroll
        for (int mi=0; mi<2; ++mi)
            #pragma unroll
            for (int ni=0; ni<8; ++ni)
                acc[mi][ni] = __builtin_amdgcn_mfma_f32_16x16x32_bf16(af[mi], bfr[ni], acc[mi][ni], 0,0,0);
        __syncthreads();
    }

    float sskip = 1.f/(1.f+__expf(-skip_l[0]));
    float osk = 1.f - sskip;
    float bv[8], gv[8], bbv[8];
    #pragma unroll
    for (int ni=0; ni<8; ++ni){
        int colg = wn*128 + ni*16 + lm;
        bv[ni]  = bias[colg];
        gv[ni]  = g[colg];
        bbv[ni] = b[colg];
    }
    #pragma unroll
    for (int mi=0; mi<2; ++mi){
        #pragma unroll
        for (int t=0; t<4; ++t){
            int lr = wm*32 + mi*16 + quad*4 + t;
            int r = row0 + lr;
            float ps = 0.f, pq = 0.f;
            #pragma unroll
            for (int ni=0; ni<8; ++ni){
                int colg = wn*128 + ni*16 + lm;
                float hv = (r < NN) ? h_in[(size_t)r*256 + colg] : 0.f;
                float val = sskip*(acc[mi][ni][t] + bv[ni]) + osk*hv;
                val = fmaxf(val, 0.f);
                acc[mi][ni][t] = val;
                ps += val; pq += val*val;
            }
            part_s[lr*33 + wn*16 + lm] = ps;
            part_q[lr*33 + wn*16 + lm] = pq;
        }
    }
    __syncthreads();
    if (tid < 64){
        float S = 0.f, Q = 0.f;
        #pragma unroll 8
        for (int t2=0; t2<32; ++t2){
            S += part_s[tid*33 + t2];
            Q += part_q[tid*33 + t2];
        }
        float mu = S * (1.f/256.f);
        float var = Q * (1.f/256.f) - mu*mu;
        mu_s[tid] = mu;
        rstd_s[tid] = rsqrtf(var + 1e-5f);
    }
    __syncthreads();
    #pragma unroll
    for (int mi=0; mi<2; ++mi){
        #pragma unroll
        for (int t=0; t<4; ++t){
            int lr = wm*32 + mi*16 + quad*4 + t;
            int r = row0 + lr;
            if (r >= NN) continue;
            float mu = mu_s[lr], rstd = rstd_s[lr];
            #pragma unroll
            for (int ni=0; ni<8; ++ni){
                int colg = wn*128 + ni*16 + lm;
                float o = (acc[mi][ni][t] - mu)*rstd*gv[ni] + bbv[ni];
                h_out[(size_t)r*256 + colg] = o;
                hbf[(size_t)(colg>>5)*APAN + (size_t)r*32 + (colg&31)] = f2bf(o);
            }
        }
    }
}

// ======================= K3b: out GEMM + skip blend (final layer) =======================
// A2 and Wto in k-panel layout
__global__ __launch_bounds__(256) void gemmO_k(const u16* __restrict__ A,
        const u16* __restrict__ Wt, const float* __restrict__ bias,
        const float* __restrict__ h_in, const float* __restrict__ skip_l,
        float* __restrict__ outp){
    __shared__ u16 As[4096];
    __shared__ u16 Bs[4096];
    int tid = threadIdx.x;
    int w = tid >> 6, lane = tid & 63;
    int row0 = blockIdx.x * 128;
    int col0 = blockIdx.y * 128;
    int wm = w & 1, wn = w >> 1;
    f32x4 acc[4][4];
    #pragma unroll
    for (int i=0;i<4;++i)
        #pragma unroll
        for (int j=0;j<4;++j) acc[i][j] = (f32x4){0.f,0.f,0.f,0.f};

    int lm = lane & 15, quad = lane >> 4;
    int kq0 = quad ^ (lm & 3);
    int aoff = (wm*64 + lm)*32 + kq0*8;
    int boff = (wn*64 + lm)*32 + kq0*8;

    for (int kk = 0; kk < 8; ++kk){
        #pragma unroll
        for (int it = 0; it < 2; ++it){
            int s = w*128 + it*64 + lane;
            int row = s >> 2, q0 = s & 3;
            int kq = q0 ^ (row & 3);
            gload_lds16(&A [(size_t)kk*APAN + (size_t)(row0+row)*32 + kq*8], &As[(size_t)(w*128 + it*64)*8]);
            gload_lds16(&Wt[(size_t)kk*OPAN + (size_t)(col0+row)*32 + kq*8], &Bs[(size_t)(w*128 + it*64)*8]);
        }
        __syncthreads();
        bf16x8 af[4], bfr[4];
        #pragma unroll
        for (int mi=0; mi<4; ++mi) af[mi]  = *(bf16x8*)&As[aoff + mi*512];
        #pragma unroll
        for (int ni=0; ni<4; ++ni) bfr[ni] = *(bf16x8*)&Bs[boff + ni*512];
        #pragma unroll
        for (int mi=0; mi<4; ++mi)
            #pragma unroll
            for (int ni=0; ni<4; ++ni)
                acc[mi][ni] = __builtin_amdgcn_mfma_f32_16x16x32_bf16(af[mi], bfr[ni], acc[mi][ni], 0,0,0);
        __syncthreads();
    }
    float s = 1.f/(1.f+expf(-skip_l[0]));
    float os = 1.f - s;
    #pragma unroll
    for (int ni=0; ni<4; ++ni){
        int colg = col0 + wn*64 + ni*16 + lm;
        float bv = bias[colg];
        #pragma unroll
        for (int mi=0; mi<4; ++mi){
            #pragma unroll
            for (int t=0; t<4; ++t){
                int r = row0 + wm*64 + mi*16 + quad*4 + t;
                if (r < NN)
                    outp[(size_t)r*256 + colg] =
                        s*(acc[mi][ni][t] + bv) + os*h_in[(size_t)r*256 + colg];
            }
        }
    }
}

// ======================= host =======================
extern "C" void kernel_launch(void* const* d_in, const int* in_sizes, int n_in,
                              void* d_out, int out_size, void* d_ws, size_t ws_size,
                              hipStream_t stream){
    (void)in_sizes; (void)n_in; (void)out_size; (void)ws_size;
    const float* x     = (const float*)d_in[0];
    const int*   ei0   = (const int*)d_in[1];
    const int*   ei1   = (const int*)d_in[2];
    const float* kqv_w = (const float*)d_in[3];
    const float* kqv_b = (const float*)d_in[4];
    const float* out_w = (const float*)d_in[5];
    const float* out_b = (const float*)d_in[6];
    const float* skip  = (const float*)d_in[7];
    const float* krel  = (const float*)d_in[8];
    const float* vrel  = (const float*)d_in[9];
    const float* prel  = (const float*)d_in[10];
    const float* ln_g  = (const float*)d_in[11];
    const float* ln_b  = (const float*)d_in[12];
    float* outp = (float*)d_out;

    char* wp = (char*)d_ws;
    auto alloc = [&](size_t bytes)->void*{
        void* p = wp; wp += (bytes + 255) & ~(size_t)255; return p;
    };
    float* hA    = (float*)alloc((size_t)NN*CC*4);
    float* hB    = (float*)alloc((size_t)NN*CC*4);
    u16*   xbf   = (u16*)alloc((size_t)NPAD*CC*2);   // k-panel layout
    u16*   hbf   = (u16*)alloc((size_t)NPAD*CC*2);   // k-panel layout
    u16*   A2    = (u16*)alloc((size_t)NPAD*CC*2);   // k-panel layout
    u16*   qb    = (u16*)alloc((size_t)NN*CC*2);
    u8*    kvb   = (u8*)alloc((size_t)2*NN*KVSTRIDE);   // [rel*NN+node][kr bf16 || vr fp8]
    u16*   Wt5   = (u16*)alloc((size_t)4*1280*256*2);   // k-panel layout
    u16*   Wto   = (u16*)alloc((size_t)4*256*256*2);    // k-panel layout
    float* bias5 = (float*)alloc((size_t)4*1280*4);
    float* sc5   = (float*)alloc((size_t)4*1280*4);
    int* cnt     = (int*)alloc((size_t)NN*4);      // cnt+cursor adjacent: one memset
    int* cursor  = (int*)alloc((size_t)NN*4);
    int* incl    = (int*)alloc((size_t)NN*4);
    int* row_ptr = (int*)alloc((size_t)(NN+1)*4);
    int* bsum    = (int*)alloc(128*4);
    int* epk     = (int*)alloc((size_t)TE*4);

    // prep (weights + input cast) — independent of CSR chain
    build_w5_k<<<5120,256,0,stream>>>(kqv_w, krel, vrel, Wt5);
    build_bias5_k<<<20,256,0,stream>>>(kqv_b, krel, vrel, prel, bias5, sc5);
    build_wo_k<<<1024,256,0,stream>>>(out_w, Wto);
    cvt_x_k<<<2500,256,0,stream>>>(x, xbf);

    // CSR build
    size_t cntBlk = ((size_t)NN*4 + 255) & ~(size_t)255;
    hipMemsetAsync(cnt, 0, cntBlk + (size_t)NN*4, stream);   // zero cnt AND cursor
    hist_k<<<1250,256,0,stream>>>(ei0, ei1, cnt);
    scan_block_k<<<79,256,0,stream>>>(cnt, incl, bsum);
    scan_bsum_k<<<1,128,0,stream>>>(bsum, 79);
    finalize_rowptr_k<<<79,256,0,stream>>>(cnt, incl, bsum, row_ptr);
    scatter_k<<<1250,256,0,stream>>>(ei0, ei1, row_ptr, cursor, epk);

    const float* h_in = x;
    const u16*   Ain  = xbf;
    float* houts[4] = {hA, hB, hA, outp};
    for (int l=0; l<4; ++l){
        gemm5_k<<<dim3(10,157),256,0,stream>>>(Ain, Wt5 + (size_t)l*327680,
                bias5 + l*1280, sc5 + l*1280, qb, kvb);
        attn_k<<<5000,256,0,stream>>>(qb, kvb, row_ptr, epk, A2);
        if (l < 3){
            gemmOln_k<<<314,256,0,stream>>>(A2, Wto + (size_t)l*65536,
                    out_b + l*256, h_in, skip + l, ln_g + l*256, ln_b + l*256,
                    houts[l], hbf);
        } else {
            gemmO_k<<<dim3(157,2),256,0,stream>>>(A2, Wto + (size_t)l*65536,
                    out_b + l*256, h_in, skip + l, outp);
        }
        h_in = houts[l];
        Ain = hbf;
    }
}

// Round 14
// 534.352 us; speedup vs baseline: 1.0277x; 1.0277x over previous
//
#include <hip/hip_runtime.h>
#include <math.h>

#define NN 20000
#define NPAD 20096          // padded rows for unguarded MFMA staging (157*128)
#define CC 256
#define HH 8
#define EE 160000
#define TE 320000
#define KVSTRIDE 768        // bytes per kv row: kr 256xbf16 (512B) + vr 256xfp8 (256B)
#define APAN ((size_t)NPAD*32)   // u16 elems per A-operand k-panel (xbf/hbf/A2)
#define BPAN 40960               // u16 elems per Wt5 k-panel (1280*32)
#define OPAN 8192                // u16 elems per Wto k-panel (256*32)

typedef unsigned short u16;
typedef unsigned char u8;
typedef __attribute__((ext_vector_type(8))) short bf16x8;
typedef __attribute__((ext_vector_type(4))) float f32x4;
typedef __attribute__((ext_vector_type(2))) float f32x2;

__device__ __forceinline__ float gelu_exact(float x){
    return 0.5f*x*(1.0f+erff(x*0.7071067811865476f));
}
__device__ __forceinline__ u16 f2bf(float f){
    unsigned u = __float_as_uint(f);
    unsigned r = (u + 0x7fffu + ((u >> 16) & 1u)) >> 16;
    return (u16)r;
}
__device__ __forceinline__ float bf2f(u16 s){
    return __uint_as_float(((unsigned)s) << 16);
}
__device__ __forceinline__ void dec8(uint4 u, float* f){
    f[0]=__uint_as_float(u.x<<16); f[1]=__uint_as_float(u.x&0xffff0000u);
    f[2]=__uint_as_float(u.y<<16); f[3]=__uint_as_float(u.y&0xffff0000u);
    f[4]=__uint_as_float(u.z<<16); f[5]=__uint_as_float(u.z&0xffff0000u);
    f[6]=__uint_as_float(u.w<<16); f[7]=__uint_as_float(u.w&0xffff0000u);
}
__device__ __forceinline__ void dec8_fp8(uint2 u, float* f){
    f32x2 a = __builtin_amdgcn_cvt_pk_f32_fp8(u.x, false);
    f32x2 b = __builtin_amdgcn_cvt_pk_f32_fp8(u.x, true);
    f32x2 c = __builtin_amdgcn_cvt_pk_f32_fp8(u.y, false);
    f32x2 d = __builtin_amdgcn_cvt_pk_f32_fp8(u.y, true);
    f[0]=a.x; f[1]=a.y; f[2]=b.x; f[3]=b.y;
    f[4]=c.x; f[5]=c.y; f[6]=d.x; f[7]=d.y;
}
__device__ __forceinline__ uint2 enc8_fp8(const float* f){
    int t0 = __builtin_amdgcn_cvt_pk_fp8_f32(f[0], f[1], 0, false);
    t0     = __builtin_amdgcn_cvt_pk_fp8_f32(f[2], f[3], t0, true);
    int t1 = __builtin_amdgcn_cvt_pk_fp8_f32(f[4], f[5], 0, false);
    t1     = __builtin_amdgcn_cvt_pk_fp8_f32(f[6], f[7], t1, true);
    uint2 r; r.x = (unsigned)t0; r.y = (unsigned)t1;
    return r;
}
__device__ __forceinline__ float dot8(const float* a, const float* b){
    return a[0]*b[0]+a[1]*b[1]+a[2]*b[2]+a[3]*b[3]
          +a[4]*b[4]+a[5]*b[5]+a[6]*b[6]+a[7]*b[7];
}
__device__ __forceinline__ void gload_lds16(const u16* gsrc, u16* lds_dst){
    __builtin_amdgcn_global_load_lds((const __attribute__((address_space(1))) unsigned int*)gsrc,
                                     (__attribute__((address_space(3))) unsigned int*)lds_dst,
                                     16, 0, 0);
}

// ======================= CSR build =======================
__global__ void hist_k(const int* __restrict__ ei0, const int* __restrict__ ei1,
                       int* __restrict__ cnt){
    int e = blockIdx.x*256 + threadIdx.x;
    if (e < TE){
        int dst = (e < EE) ? ei0[EE + e] : ei1[EE + (e - EE)];
        atomicAdd(&cnt[dst], 1);
    }
}
__global__ void scan_block_k(const int* __restrict__ cnt, int* __restrict__ incl,
                             int* __restrict__ bsum){
    __shared__ int tmp[256];
    int tid = threadIdx.x;
    int i = blockIdx.x*256 + tid;
    int v = (i < NN) ? cnt[i] : 0;
    tmp[tid] = v;
    __syncthreads();
    for (int d=1; d<256; d<<=1){
        int t = (tid>=d) ? tmp[tid-d] : 0;
        __syncthreads();
        tmp[tid] += t;
        __syncthreads();
    }
    if (i < NN) incl[i] = tmp[tid];
    if (tid == 255) bsum[blockIdx.x] = tmp[255];
}
__global__ void scan_bsum_k(int* bsum, int nb){
    __shared__ int tmp[128];
    int tid = threadIdx.x;
    int v = (tid < nb) ? bsum[tid] : 0;
    tmp[tid] = v;
    __syncthreads();
    for (int d=1; d<128; d<<=1){
        int t = (tid>=d) ? tmp[tid-d] : 0;
        __syncthreads();
        tmp[tid] += t;
        __syncthreads();
    }
    if (tid < nb) bsum[tid] = tmp[tid] - v;   // exclusive
}
__global__ void finalize_rowptr_k(const int* __restrict__ cnt, const int* __restrict__ incl,
                                  const int* __restrict__ bsum, int* __restrict__ row_ptr){
    int i = blockIdx.x*256 + threadIdx.x;
    if (i < NN) row_ptr[i] = incl[i] - cnt[i] + bsum[blockIdx.x];
    if (i == NN) row_ptr[NN] = TE;
}
// stores the final kv-row index rel*NN+src per CSR slot
__global__ void scatter_k(const int* __restrict__ ei0, const int* __restrict__ ei1,
                          const int* __restrict__ row_ptr, int* __restrict__ cursor,
                          int* __restrict__ epk){
    int e = blockIdx.x*256 + threadIdx.x;
    if (e < TE){
        int src, dst, rel;
        if (e < EE){ src = ei0[e]; dst = ei0[EE+e]; rel = 0; }
        else { int ee=e-EE; src = ei1[ee]; dst = ei1[EE+ee]; rel = 1; }
        int pos = atomicAdd(&cursor[dst], 1);
        epk[row_ptr[dst] + pos] = rel*NN + src;
    }
}

// ======================= weight prep =======================
// Wt5 in k-panel layout: [l][kpanel 0..7][n 0..1279][32k]
__global__ void build_w5_k(const float* __restrict__ kqv_w, const float* __restrict__ krel,
                           const float* __restrict__ vrel, u16* __restrict__ Wt){
    int idx = blockIdx.x*256 + threadIdx.x;        // 4*1280*256
    int k = idx & 255;
    int n = (idx >> 8) % 1280;
    int l = idx / (1280*256);
    const float* W = kqv_w + (size_t)l*196608;     // [256][768]
    float val;
    if (n < 256){
        val = W[k*768 + 256 + n];
    } else {
        int g = (n-256) >> 8;
        int r = g & 1, isv = g >> 1;
        int c = (n-256) & 255;
        int h = c >> 5, f = c & 31;
        const float* Rm = (isv ? vrel : krel) + ((size_t)l*2 + r)*8192 + h*1024; // [32][32]
        int base = isv ? 512 : 0;
        float a = 0.f;
        #pragma unroll 8
        for (int d=0; d<32; ++d)
            a += W[k*768 + base + h*32 + d] * Rm[d*32 + f];
        val = a;
    }
    Wt[(size_t)l*327680 + (size_t)(k>>5)*BPAN + n*32 + (k&31)] = f2bf(val);
}
// bias5 (pre-rel bias) + per-col scale (prel/sqrt(DH) folded into kr cols)
__global__ void build_bias5_k(const float* __restrict__ kqv_b, const float* __restrict__ krel,
                              const float* __restrict__ vrel, const float* __restrict__ prel,
                              float* __restrict__ bias5, float* __restrict__ sc5){
    int idx = blockIdx.x*256 + threadIdx.x;        // 4*1280
    if (idx >= 4*1280) return;
    int n = idx % 1280, l = idx / 1280;
    const float* B = kqv_b + l*768;
    float val, scl = 1.f;
    if (n < 256) val = B[256+n];
    else {
        int g = (n-256) >> 8;
        int r = g & 1, isv = g >> 1;
        int c = (n-256) & 255;
        int h = c >> 5, f = c & 31;
        const float* Rm = (isv ? vrel : krel) + ((size_t)l*2 + r)*8192 + h*1024;
        int base = isv ? 512 : 0;
        float a = 0.f;
        for (int d=0; d<32; ++d) a += B[base + h*32 + d] * Rm[d*32 + f];
        val = a;
        if (!isv) scl = prel[l*16 + r*8 + h] * 0.17677669529663687f;
    }
    bias5[idx] = val;
    sc5[idx] = scl;
}
// out_w [l][k][n] fp32 -> Wto k-panels [l][kpanel][n][32k] bf16
__global__ void build_wo_k(const float* __restrict__ out_w, u16* __restrict__ Wto){
    int idx = blockIdx.x*256 + threadIdx.x;        // 4*256*256
    int k = idx & 255;
    int n = (idx >> 8) & 255;
    int l = idx >> 16;
    Wto[(size_t)l*65536 + (size_t)(k>>5)*OPAN + n*32 + (k&31)] =
        f2bf(out_w[(size_t)l*65536 + k*256 + n]);
}
// x fp32 row-major -> xbf bf16 k-panels [kpanel][row][32k]
__global__ void cvt_x_k(const float* __restrict__ x, u16* __restrict__ xbf){
    int idx = blockIdx.x*256 + threadIdx.x;        // 640000 (8 elems each)
    int e = idx*8;
    int row = e >> 8, col = e & 255;
    const float4* xp = (const float4*)x;
    float4 a = xp[(size_t)idx*2], b = xp[(size_t)idx*2+1];
    uint4 o;
    o.x = (unsigned)f2bf(a.x) | ((unsigned)f2bf(a.y)<<16);
    o.y = (unsigned)f2bf(a.z) | ((unsigned)f2bf(a.w)<<16);
    o.z = (unsigned)f2bf(b.x) | ((unsigned)f2bf(b.y)<<16);
    o.w = (unsigned)f2bf(b.z) | ((unsigned)f2bf(b.w)<<16);
    *(uint4*)&xbf[(size_t)(col>>5)*APAN + (size_t)row*32 + (col&31)] = o;
}

// ======================= K1: 5-output MFMA GEMM (panel-staged, XCD-clustered) =========
// 1D grid of 1600; with HW round-robin block->XCD, L&7 selects the XCD, and each
// XCD gets a CONTIGUOUS 20-row-tile strip of A (1.28 MB) + whole Wt (0.65 MB):
// both L2-resident per XCD -> staged loads hit L2 instead of re-fetching A ~4x.
__global__ __launch_bounds__(256) void gemm5_k(const u16* __restrict__ A,
        const u16* __restrict__ Wt, const float* __restrict__ biasp,
        const float* __restrict__ sc5p,
        u16* __restrict__ qb, u8* __restrict__ kvb){
    int L = blockIdx.x;
    int xcd = L & 7;
    int t = L >> 3;                  // 0..199
    int ytile = xcd*20 + t/10;       // 0..159
    int xtile = t % 10;
    if (ytile >= 157) return;        // uniform per block (before any barrier)
    int col0 = xtile * 128;
    int row0 = ytile * 128;

    __shared__ __align__(16) char smem[33792];   // max(As+Bs=16K, Cs=128*66*4)
    u16* As = (u16*)smem;                        // 4096 u16
    u16* Bs = (u16*)(smem + 8192);               // 4096 u16
    float* Cs = (float*)smem;                    // 128*66 (aliases As/Bs post-K-loop)
    int tid = threadIdx.x;
    int w = tid >> 6, lane = tid & 63;
    int wm = w & 1, wn = w >> 1;
    f32x4 acc[4][4];
    #pragma unroll
    for (int i=0;i<4;++i)
        #pragma unroll
        for (int j=0;j<4;++j) acc[i][j] = (f32x4){0.f,0.f,0.f,0.f};

    int lm = lane & 15, quad = lane >> 4;
    int kq0 = quad ^ (lm & 3);
    int aoff = (wm*64 + lm)*32 + kq0*8;
    int boff = (wn*64 + lm)*32 + kq0*8;

    for (int kk = 0; kk < 8; ++kk){
        #pragma unroll
        for (int it = 0; it < 2; ++it){
            int s = w*128 + it*64 + lane;      // 16B slot id (0..511)
            int row = s >> 2, q0 = s & 3;
            int kq = q0 ^ (row & 3);           // write-side swizzle via source addr
            gload_lds16(&A [(size_t)kk*APAN + (size_t)(row0+row)*32 + kq*8], &As[(size_t)(w*128 + it*64)*8]);
            gload_lds16(&Wt[(size_t)kk*BPAN + (size_t)(col0+row)*32 + kq*8], &Bs[(size_t)(w*128 + it*64)*8]);
        }
        __syncthreads();
        bf16x8 af[4], bfr[4];
        #pragma unroll
        for (int mi=0; mi<4; ++mi) af[mi]  = *(bf16x8*)&As[aoff + mi*512];
        #pragma unroll
        for (int ni=0; ni<4; ++ni) bfr[ni] = *(bf16x8*)&Bs[boff + ni*512];
        #pragma unroll
        for (int mi=0; mi<4; ++mi)
            #pragma unroll
            for (int ni=0; ni<4; ++ni)
                acc[mi][ni] = __builtin_amdgcn_mfma_f32_16x16x32_bf16(af[mi], bfr[ni], acc[mi][ni], 0,0,0);
        __syncthreads();    // last iteration also fences As/Bs before Cs aliasing
    }

    int bufi = col0 >> 8;   // 0:q 1:kr0 2:kr1 3:vr0 4:vr1 (uniform per block)
    int cbase = col0 & 255;
    float bvv[4], scv[4];
    #pragma unroll
    for (int ni=0; ni<4; ++ni){
        bvv[ni] = biasp[col0 + wn*64 + ni*16 + lm];
        scv[ni] = sc5p [col0 + wn*64 + ni*16 + lm];
    }

    int rowl_s = tid >> 3;              // 0..31
    int col8   = tid & 7;               // 0..7 (8 lcols each)
    int gcb    = (col8 >> 2)*64 + (col8 & 3)*8;

    #pragma unroll
    for (int p=0; p<2; ++p){
        if (p) __syncthreads();
        #pragma unroll
        for (int nj=0; nj<2; ++nj){
            int ni = p*2 + nj;
            int lcol = wn*32 + nj*16 + lm;
            #pragma unroll
            for (int mi=0; mi<4; ++mi){
                #pragma unroll
                for (int t2=0; t2<4; ++t2){
                    int lr = wm*64 + mi*16 + quad*4 + t2;
                    Cs[lr*66 + lcol] = (acc[mi][ni][t2] + bvv[ni]) * scv[ni];
                }
            }
        }
        __syncthreads();
        int cw = cbase + gcb + p*32;
        #pragma unroll
        for (int it=0; it<4; ++it){
            int rl = rowl_s + it*32;
            int r = row0 + rl;
            if (r < NN){
                const float* src = &Cs[rl*66 + col8*8];
                float cf[8];
                *(float4*)&cf[0] = *(const float4*)&src[0];
                *(float4*)&cf[4] = *(const float4*)&src[4];
                if (bufi == 0){
                    uint4 o;
                    o.x = (unsigned)f2bf(cf[0]) | ((unsigned)f2bf(cf[1])<<16);
                    o.y = (unsigned)f2bf(cf[2]) | ((unsigned)f2bf(cf[3])<<16);
                    o.z = (unsigned)f2bf(cf[4]) | ((unsigned)f2bf(cf[5])<<16);
                    o.w = (unsigned)f2bf(cf[6]) | ((unsigned)f2bf(cf[7])<<16);
                    *(uint4*)&qb[(size_t)r*256 + cw] = o;
                } else if (bufi <= 2){
                    int rel = bufi - 1;
                    uint4 o;
                    o.x = (unsigned)f2bf(cf[0]) | ((unsigned)f2bf(cf[1])<<16);
                    o.y = (unsigned)f2bf(cf[2]) | ((unsigned)f2bf(cf[3])<<16);
                    o.z = (unsigned)f2bf(cf[4]) | ((unsigned)f2bf(cf[5])<<16);
                    o.w = (unsigned)f2bf(cf[6]) | ((unsigned)f2bf(cf[7])<<16);
                    *(uint4*)&kvb[(size_t)(rel*NN + r)*KVSTRIDE + cw*2] = o;
                } else {
                    int rel = bufi - 3;
                    uint2 o = enc8_fp8(cf);
                    *(uint2*)&kvb[(size_t)(rel*NN + r)*KVSTRIDE + 512 + cw] = o;
                }
            }
        }
    }
}

// ======================= K2: split-wave CSR attention, online softmax ==============
// A2 output in k-panel layout (A operand of gemmOln/gemmO)
__global__ __launch_bounds__(256) void attn_k(const u16* __restrict__ qb,
        const u8* __restrict__ kvb,
        const int* __restrict__ row_ptr, const int* __restrict__ epk,
        u16* __restrict__ A2){
    int wv = threadIdx.x >> 6, lane = threadIdx.x & 63;
    int node = blockIdx.x*4 + wv;
    int l32 = lane & 31;
    int half = lane >> 5;
    int start = row_ptr[node], end = row_ptr[node+1];
    float qf[8];
    {
        uint4 qr = *(const uint4*)&qb[(size_t)node*256 + l32*8];
        dec8(qr, qf);
    }
    float m = -1e30f, s = 0.f;
    float acc[8] = {0.f,0.f,0.f,0.f,0.f,0.f,0.f,0.f};

    int i0 = start + half;
    uint4 k0={0,0,0,0}, k1={0,0,0,0};
    uint2 v0={0,0}, v1={0,0};
    if (i0 < end){
        const u8* row = &kvb[(size_t)epk[i0]*KVSTRIDE];
        k0 = *(const uint4*)(row + l32*16);
        v0 = *(const uint2*)(row + 512 + l32*8);
    }
    if (i0 + 2 < end){
        const u8* row = &kvb[(size_t)epk[i0+2]*KVSTRIDE];
        k1 = *(const uint4*)(row + l32*16);
        v1 = *(const uint2*)(row + 512 + l32*8);
    }
    int pk = (i0 + 4 < end) ? epk[i0+4] : 0;

    for (int i = i0; i < end; i += 2){
        uint4 kc = k0;
        uint2 vc = v0;
        k0 = k1; v0 = v1;
        if (i + 4 < end){                      // refill depth-2 slot
            const u8* row = &kvb[(size_t)pk*KVSTRIDE];
            k1 = *(const uint4*)(row + l32*16);
            v1 = *(const uint2*)(row + 512 + l32*8);
        }
        if (i + 6 < end) pk = epk[i+6];        // index 3 deep
        float kv[8];
        dec8(kc, kv);
        float p = dot8(qf, kv);
        p += __shfl_xor(p, 1);
        p += __shfl_xor(p, 2);                 // logit (prel/sqrt folded into kr)
        float mo = m;
        m = fmaxf(m, p);
        float sc = __expf(mo - m);
        float pe = __expf(p - m);
        s = s*sc + pe;
        float vv[8];
        dec8_fp8(vc, vv);
        #pragma unroll
        for (int j=0;j<8;++j) acc[j] = acc[j]*sc + pe*vv[j];
    }
    // merge the two halves' online-softmax states (m=-1e30: no inf-inf NaN)
    float mO = __shfl_xor(m, 32);
    float mA = fmaxf(m, mO);
    float eS = __expf(m - mA);
    float sh = s * eS;
    float sA = sh + __shfl_xor(sh, 32);
    float rs = 1.f / fmaxf(sA, 1e-16f);
    float oA[8];
    #pragma unroll
    for (int j=0;j<8;++j){
        float a = acc[j] * eS;
        oA[j] = a + __shfl_xor(a, 32);
    }
    if (half == 0){
        u16 o[8];
        #pragma unroll
        for (int j=0;j<8;++j) o[j] = f2bf(gelu_exact(oA[j]*rs));
        uint4 ov;
        ov.x = (unsigned)o[0] | ((unsigned)o[1]<<16);
        ov.y = (unsigned)o[2] | ((unsigned)o[3]<<16);
        ov.z = (unsigned)o[4] | ((unsigned)o[5]<<16);
        ov.w = (unsigned)o[6] | ((unsigned)o[7]<<16);
        int c0 = l32*8;
        *(uint4*)&A2[(size_t)(c0>>5)*APAN + (size_t)node*32 + (c0&31)] = ov;
    }
}

// ======================= K3a: out GEMM + skip + relu + LN (layers 0-2) ===========
// A2 and Wto in k-panel layout -> contiguous staging runs.
// emits h_out fp32 (row-major) and hbf bf16 k-panels for next gemm5
__global__ __launch_bounds__(256) void gemmOln_k(const u16* __restrict__ A,
        const u16* __restrict__ Wt, const float* __restrict__ bias,
        const float* __restrict__ h_in, const float* __restrict__ skip_l,
        const float* __restrict__ g, const float* __restrict__ b,
        float* __restrict__ h_out, u16* __restrict__ hbf){
    __shared__ u16 As[2048];          // 64 rows x 32 k
    __shared__ u16 Bs[8192];          // 256 cols x 32 k
    __shared__ float part_s[64*33];
    __shared__ float part_q[64*33];
    __shared__ float mu_s[64], rstd_s[64];
    int tid = threadIdx.x;
    int w = tid >> 6, lane = tid & 63;
    int row0 = blockIdx.x * 64;
    int wm = w & 1, wn = w >> 1;
    f32x4 acc[2][8];
    #pragma unroll
    for (int i=0;i<2;++i)
        #pragma unroll
        for (int j=0;j<8;++j) acc[i][j] = (f32x4){0.f,0.f,0.f,0.f};

    int lm = lane & 15, quad = lane >> 4;
    int kq0 = quad ^ (lm & 3);
    int aoff = (wm*32 + lm)*32 + kq0*8;
    int boff = (wn*128 + lm)*32 + kq0*8;

    for (int kk = 0; kk < 8; ++kk){
        {
            int s = tid;                       // 256 slots = 64 rows x 4
            int row = s >> 2, q0 = s & 3;
            int kq = q0 ^ (row & 3);
            gload_lds16(&A[(size_t)kk*APAN + (size_t)(row0+row)*32 + kq*8], &As[(size_t)(w*64)*8]);
        }
        #pragma unroll
        for (int it = 0; it < 4; ++it){        // 1024 slots = 256 n-rows x 4
            int s = it*256 + w*64 + lane;
            int row = s >> 2, q0 = s & 3;
            int kq = q0 ^ (row & 3);
            gload_lds16(&Wt[(size_t)kk*OPAN + (size_t)row*32 + kq*8], &Bs[(size_t)(it*256 + w*64)*8]);
        }
        __syncthreads();
        bf16x8 af[2], bfr[8];
        #pragma unroll
        for (int mi=0; mi<2; ++mi) af[mi]  = *(bf16x8*)&As[aoff + mi*512];
        #pragma unroll
        for (int ni=0; ni<8; ++ni) bfr[ni] = *(bf16x8*)&Bs[boff + ni*512];
        #pragma unroll
        for (int mi=0; mi<2; ++mi)
            #pragma unroll
            for (int ni=0; ni<8; ++ni)
                acc[mi][ni] = __builtin_amdgcn_mfma_f32_16x16x32_bf16(af[mi], bfr[ni], acc[mi][ni], 0,0,0);
        __syncthreads();
    }

    float sskip = 1.f/(1.f+__expf(-skip_l[0]));
    float osk = 1.f - sskip;
    float bv[8], gv[8], bbv[8];
    #pragma unroll
    for (int ni=0; ni<8; ++ni){
        int colg = wn*128 + ni*16 + lm;
        bv[ni]  = bias[colg];
        gv[ni]  = g[colg];
        bbv[ni] = b[colg];
    }
    #pragma unroll
    for (int mi=0; mi<2; ++mi){
        #pragma unroll
        for (int t=0; t<4; ++t){
            int lr = wm*32 + mi*16 + quad*4 + t;
            int r = row0 + lr;
            float ps = 0.f, pq = 0.f;
            #pragma unroll
            for (int ni=0; ni<8; ++ni){
                int colg = wn*128 + ni*16 + lm;
                float hv = (r < NN) ? h_in[(size_t)r*256 + colg] : 0.f;
                float val = sskip*(acc[mi][ni][t] + bv[ni]) + osk*hv;
                val = fmaxf(val, 0.f);
                acc[mi][ni][t] = val;
                ps += val; pq += val*val;
            }
            part_s[lr*33 + wn*16 + lm] = ps;
            part_q[lr*33 + wn*16 + lm] = pq;
        }
    }
    __syncthreads();
    if (tid < 64){
        float S = 0.f, Q = 0.f;
        #pragma unroll 8
        for (int t2=0; t2<32; ++t2){
            S += part_s[tid*33 + t2];
            Q += part_q[tid*33 + t2];
        }
        float mu = S * (1.f/256.f);
        float var = Q * (1.f/256.f) - mu*mu;
        mu_s[tid] = mu;
        rstd_s[tid] = rsqrtf(var + 1e-5f);
    }
    __syncthreads();
    #pragma unroll
    for (int mi=0; mi<2; ++mi){
        #pragma unroll
        for (int t=0; t<4; ++t){
            int lr = wm*32 + mi*16 + quad*4 + t;
            int r = row0 + lr;
            if (r >= NN) continue;
            float mu = mu_s[lr], rstd = rstd_s[lr];
            #pragma unroll
            for (int ni=0; ni<8; ++ni){
                int colg = wn*128 + ni*16 + lm;
                float o = (acc[mi][ni][t] - mu)*rstd*gv[ni] + bbv[ni];
                h_out[(size_t)r*256 + colg] = o;
                hbf[(size_t)(colg>>5)*APAN + (size_t)r*32 + (colg&31)] = f2bf(o);
            }
        }
    }
}

// ======================= K3b: out GEMM + skip blend (final layer) =======================
// A2 and Wto in k-panel layout
__global__ __launch_bounds__(256) void gemmO_k(const u16* __restrict__ A,
        const u16* __restrict__ Wt, const float* __restrict__ bias,
        const float* __restrict__ h_in, const float* __restrict__ skip_l,
        float* __restrict__ outp){
    __shared__ u16 As[4096];
    __shared__ u16 Bs[4096];
    int tid = threadIdx.x;
    int w = tid >> 6, lane = tid & 63;
    int row0 = blockIdx.x * 128;
    int col0 = blockIdx.y * 128;
    int wm = w & 1, wn = w >> 1;
    f32x4 acc[4][4];
    #pragma unroll
    for (int i=0;i<4;++i)
        #pragma unroll
        for (int j=0;j<4;++j) acc[i][j] = (f32x4){0.f,0.f,0.f,0.f};

    int lm = lane & 15, quad = lane >> 4;
    int kq0 = quad ^ (lm & 3);
    int aoff = (wm*64 + lm)*32 + kq0*8;
    int boff = (wn*64 + lm)*32 + kq0*8;

    for (int kk = 0; kk < 8; ++kk){
        #pragma unroll
        for (int it = 0; it < 2; ++it){
            int s = w*128 + it*64 + lane;
            int row = s >> 2, q0 = s & 3;
            int kq = q0 ^ (row & 3);
            gload_lds16(&A [(size_t)kk*APAN + (size_t)(row0+row)*32 + kq*8], &As[(size_t)(w*128 + it*64)*8]);
            gload_lds16(&Wt[(size_t)kk*OPAN + (size_t)(col0+row)*32 + kq*8], &Bs[(size_t)(w*128 + it*64)*8]);
        }
        __syncthreads();
        bf16x8 af[4], bfr[4];
        #pragma unroll
        for (int mi=0; mi<4; ++mi) af[mi]  = *(bf16x8*)&As[aoff + mi*512];
        #pragma unroll
        for (int ni=0; ni<4; ++ni) bfr[ni] = *(bf16x8*)&Bs[boff + ni*512];
        #pragma unroll
        for (int mi=0; mi<4; ++mi)
            #pragma unroll
            for (int ni=0; ni<4; ++ni)
                acc[mi][ni] = __builtin_amdgcn_mfma_f32_16x16x32_bf16(af[mi], bfr[ni], acc[mi][ni], 0,0,0);
        __syncthreads();
    }
    float s = 1.f/(1.f+expf(-skip_l[0]));
    float os = 1.f - s;
    #pragma unroll
    for (int ni=0; ni<4; ++ni){
        int colg = col0 + wn*64 + ni*16 + lm;
        float bv = bias[colg];
        #pragma unroll
        for (int mi=0; mi<4; ++mi){
            #pragma unroll
            for (int t=0; t<4; ++t){
                int r = row0 + wm*64 + mi*16 + quad*4 + t;
                if (r < NN)
                    outp[(size_t)r*256 + colg] =
                        s*(acc[mi][ni][t] + bv) + os*h_in[(size_t)r*256 + colg];
            }
        }
    }
}

// ======================= host =======================
extern "C" void kernel_launch(void* const* d_in, const int* in_sizes, int n_in,
                              void* d_out, int out_size, void* d_ws, size_t ws_size,
                              hipStream_t stream){
    (void)in_sizes; (void)n_in; (void)out_size; (void)ws_size;
    const float* x     = (const float*)d_in[0];
    const int*   ei0   = (const int*)d_in[1];
    const int*   ei1   = (const int*)d_in[2];
    const float* kqv_w = (const float*)d_in[3];
    const float* kqv_b = (const float*)d_in[4];
    const float* out_w = (const float*)d_in[5];
    const float* out_b = (const float*)d_in[6];
    const float* skip  = (const float*)d_in[7];
    const float* krel  = (const float*)d_in[8];
    const float* vrel  = (const float*)d_in[9];
    const float* prel  = (const float*)d_in[10];
    const float* ln_g  = (const float*)d_in[11];
    const float* ln_b  = (const float*)d_in[12];
    float* outp = (float*)d_out;

    char* wp = (char*)d_ws;
    auto alloc = [&](size_t bytes)->void*{
        void* p = wp; wp += (bytes + 255) & ~(size_t)255; return p;
    };
    float* hA    = (float*)alloc((size_t)NN*CC*4);
    float* hB    = (float*)alloc((size_t)NN*CC*4);
    u16*   xbf   = (u16*)alloc((size_t)NPAD*CC*2);   // k-panel layout
    u16*   hbf   = (u16*)alloc((size_t)NPAD*CC*2);   // k-panel layout
    u16*   A2    = (u16*)alloc((size_t)NPAD*CC*2);   // k-panel layout
    u16*   qb    = (u16*)alloc((size_t)NN*CC*2);
    u8*    kvb   = (u8*)alloc((size_t)2*NN*KVSTRIDE);   // [rel*NN+node][kr bf16 || vr fp8]
    u16*   Wt5   = (u16*)alloc((size_t)4*1280*256*2);   // k-panel layout
    u16*   Wto   = (u16*)alloc((size_t)4*256*256*2);    // k-panel layout
    float* bias5 = (float*)alloc((size_t)4*1280*4);
    float* sc5   = (float*)alloc((size_t)4*1280*4);
    int* cnt     = (int*)alloc((size_t)NN*4);      // cnt+cursor adjacent: one memset
    int* cursor  = (int*)alloc((size_t)NN*4);
    int* incl    = (int*)alloc((size_t)NN*4);
    int* row_ptr = (int*)alloc((size_t)(NN+1)*4);
    int* bsum    = (int*)alloc(128*4);
    int* epk     = (int*)alloc((size_t)TE*4);

    // prep (weights + input cast) — independent of CSR chain
    build_w5_k<<<5120,256,0,stream>>>(kqv_w, krel, vrel, Wt5);
    build_bias5_k<<<20,256,0,stream>>>(kqv_b, krel, vrel, prel, bias5, sc5);
    build_wo_k<<<1024,256,0,stream>>>(out_w, Wto);
    cvt_x_k<<<2500,256,0,stream>>>(x, xbf);

    // CSR build
    size_t cntBlk = ((size_t)NN*4 + 255) & ~(size_t)255;
    hipMemsetAsync(cnt, 0, cntBlk + (size_t)NN*4, stream);   // zero cnt AND cursor
    hist_k<<<1250,256,0,stream>>>(ei0, ei1, cnt);
    scan_block_k<<<79,256,0,stream>>>(cnt, incl, bsum);
    scan_bsum_k<<<1,128,0,stream>>>(bsum, 79);
    finalize_rowptr_k<<<79,256,0,stream>>>(cnt, incl, bsum, row_ptr);
    scatter_k<<<1250,256,0,stream>>>(ei0, ei1, row_ptr, cursor, epk);

    const float* h_in = x;
    const u16*   Ain  = xbf;
    float* houts[4] = {hA, hB, hA, outp};
    for (int l=0; l<4; ++l){
        gemm5_k<<<1600,256,0,stream>>>(Ain, Wt5 + (size_t)l*327680,
                bias5 + l*1280, sc5 + l*1280, qb, kvb);
        attn_k<<<5000,256,0,stream>>>(qb, kvb, row_ptr, epk, A2);
        if (l < 3){
            gemmOln_k<<<314,256,0,stream>>>(A2, Wto + (size_t)l*65536,
                    out_b + l*256, h_in, skip + l, ln_g + l*256, ln_b + l*256,
                    houts[l], hbf);
        } else {
            gemmO_k<<<dim3(157,2),256,0,stream>>>(A2, Wto + (size_t)l*65536,
                    out_b + l*256, h_in, skip + l, outp);
        }
        h_in = houts[l];
        Ain = hbf;
    }
}

// Round 15
// 498.286 us; speedup vs baseline: 1.1021x; 1.0724x over previous
//
#include <hip/hip_runtime.h>
#include <math.h>

#define NN 20000
#define NPAD 20096          // padded rows for unguarded MFMA staging (157*128)
#define CC 256
#define HH 8
#define EE 160000
#define TE 320000
#define KVSTRIDE 512        // bytes per kv row: kr 256xfp8 (256B) + vr 256xfp8 (256B)
#define APAN ((size_t)NPAD*32)   // u16 elems per A-operand k-panel (xbf/hbf/A2)
#define BPAN 40960               // u16 elems per Wt5 k-panel (1280*32)
#define OPAN 8192                // u16 elems per Wto k-panel (256*32)

typedef unsigned short u16;
typedef unsigned char u8;
typedef __attribute__((ext_vector_type(8))) short bf16x8;
typedef __attribute__((ext_vector_type(4))) float f32x4;
typedef __attribute__((ext_vector_type(2))) float f32x2;

__device__ __forceinline__ float gelu_exact(float x){
    return 0.5f*x*(1.0f+erff(x*0.7071067811865476f));
}
__device__ __forceinline__ u16 f2bf(float f){
    unsigned u = __float_as_uint(f);
    unsigned r = (u + 0x7fffu + ((u >> 16) & 1u)) >> 16;
    return (u16)r;
}
__device__ __forceinline__ float bf2f(u16 s){
    return __uint_as_float(((unsigned)s) << 16);
}
__device__ __forceinline__ void dec8(uint4 u, float* f){
    f[0]=__uint_as_float(u.x<<16); f[1]=__uint_as_float(u.x&0xffff0000u);
    f[2]=__uint_as_float(u.y<<16); f[3]=__uint_as_float(u.y&0xffff0000u);
    f[4]=__uint_as_float(u.z<<16); f[5]=__uint_as_float(u.z&0xffff0000u);
    f[6]=__uint_as_float(u.w<<16); f[7]=__uint_as_float(u.w&0xffff0000u);
}
__device__ __forceinline__ void dec8_fp8(uint2 u, float* f){
    f32x2 a = __builtin_amdgcn_cvt_pk_f32_fp8(u.x, false);
    f32x2 b = __builtin_amdgcn_cvt_pk_f32_fp8(u.x, true);
    f32x2 c = __builtin_amdgcn_cvt_pk_f32_fp8(u.y, false);
    f32x2 d = __builtin_amdgcn_cvt_pk_f32_fp8(u.y, true);
    f[0]=a.x; f[1]=a.y; f[2]=b.x; f[3]=b.y;
    f[4]=c.x; f[5]=c.y; f[6]=d.x; f[7]=d.y;
}
__device__ __forceinline__ uint2 enc8_fp8(const float* f){
    int t0 = __builtin_amdgcn_cvt_pk_fp8_f32(f[0], f[1], 0, false);
    t0     = __builtin_amdgcn_cvt_pk_fp8_f32(f[2], f[3], t0, true);
    int t1 = __builtin_amdgcn_cvt_pk_fp8_f32(f[4], f[5], 0, false);
    t1     = __builtin_amdgcn_cvt_pk_fp8_f32(f[6], f[7], t1, true);
    uint2 r; r.x = (unsigned)t0; r.y = (unsigned)t1;
    return r;
}
__device__ __forceinline__ float dot8(const float* a, const float* b){
    return a[0]*b[0]+a[1]*b[1]+a[2]*b[2]+a[3]*b[3]
          +a[4]*b[4]+a[5]*b[5]+a[6]*b[6]+a[7]*b[7];
}
__device__ __forceinline__ void gload_lds16(const u16* gsrc, u16* lds_dst){
    __builtin_amdgcn_global_load_lds((const __attribute__((address_space(1))) unsigned int*)gsrc,
                                     (__attribute__((address_space(3))) unsigned int*)lds_dst,
                                     16, 0, 0);
}

// ======================= CSR build =======================
__global__ void hist_k(const int* __restrict__ ei0, const int* __restrict__ ei1,
                       int* __restrict__ cnt){
    int e = blockIdx.x*256 + threadIdx.x;
    if (e < TE){
        int dst = (e < EE) ? ei0[EE + e] : ei1[EE + (e - EE)];
        atomicAdd(&cnt[dst], 1);
    }
}
__global__ void scan_block_k(const int* __restrict__ cnt, int* __restrict__ incl,
                             int* __restrict__ bsum){
    __shared__ int tmp[256];
    int tid = threadIdx.x;
    int i = blockIdx.x*256 + tid;
    int v = (i < NN) ? cnt[i] : 0;
    tmp[tid] = v;
    __syncthreads();
    for (int d=1; d<256; d<<=1){
        int t = (tid>=d) ? tmp[tid-d] : 0;
        __syncthreads();
        tmp[tid] += t;
        __syncthreads();
    }
    if (i < NN) incl[i] = tmp[tid];
    if (tid == 255) bsum[blockIdx.x] = tmp[255];
}
__global__ void scan_bsum_k(int* bsum, int nb){
    __shared__ int tmp[128];
    int tid = threadIdx.x;
    int v = (tid < nb) ? bsum[tid] : 0;
    tmp[tid] = v;
    __syncthreads();
    for (int d=1; d<128; d<<=1){
        int t = (tid>=d) ? tmp[tid-d] : 0;
        __syncthreads();
        tmp[tid] += t;
        __syncthreads();
    }
    if (tid < nb) bsum[tid] = tmp[tid] - v;   // exclusive
}
__global__ void finalize_rowptr_k(const int* __restrict__ cnt, const int* __restrict__ incl,
                                  const int* __restrict__ bsum, int* __restrict__ row_ptr){
    int i = blockIdx.x*256 + threadIdx.x;
    if (i < NN) row_ptr[i] = incl[i] - cnt[i] + bsum[blockIdx.x];
    if (i == NN) row_ptr[NN] = TE;
}
// stores the final kv-row index rel*NN+src per CSR slot
__global__ void scatter_k(const int* __restrict__ ei0, const int* __restrict__ ei1,
                          const int* __restrict__ row_ptr, int* __restrict__ cursor,
                          int* __restrict__ epk){
    int e = blockIdx.x*256 + threadIdx.x;
    if (e < TE){
        int src, dst, rel;
        if (e < EE){ src = ei0[e]; dst = ei0[EE+e]; rel = 0; }
        else { int ee=e-EE; src = ei1[ee]; dst = ei1[EE+ee]; rel = 1; }
        int pos = atomicAdd(&cursor[dst], 1);
        epk[row_ptr[dst] + pos] = rel*NN + src;
    }
}

// ======================= weight prep =======================
// Wt5 in k-panel layout: [l][kpanel 0..7][n 0..1279][32k]
__global__ void build_w5_k(const float* __restrict__ kqv_w, const float* __restrict__ krel,
                           const float* __restrict__ vrel, u16* __restrict__ Wt){
    int idx = blockIdx.x*256 + threadIdx.x;        // 4*1280*256
    int k = idx & 255;
    int n = (idx >> 8) % 1280;
    int l = idx / (1280*256);
    const float* W = kqv_w + (size_t)l*196608;     // [256][768]
    float val;
    if (n < 256){
        val = W[k*768 + 256 + n];
    } else {
        int g = (n-256) >> 8;
        int r = g & 1, isv = g >> 1;
        int c = (n-256) & 255;
        int h = c >> 5, f = c & 31;
        const float* Rm = (isv ? vrel : krel) + ((size_t)l*2 + r)*8192 + h*1024; // [32][32]
        int base = isv ? 512 : 0;
        float a = 0.f;
        #pragma unroll 8
        for (int d=0; d<32; ++d)
            a += W[k*768 + base + h*32 + d] * Rm[d*32 + f];
        val = a;
    }
    Wt[(size_t)l*327680 + (size_t)(k>>5)*BPAN + n*32 + (k&31)] = f2bf(val);
}
// bias5 (pre-rel bias) + per-col scale (prel/sqrt(DH) folded into kr cols)
__global__ void build_bias5_k(const float* __restrict__ kqv_b, const float* __restrict__ krel,
                              const float* __restrict__ vrel, const float* __restrict__ prel,
                              float* __restrict__ bias5, float* __restrict__ sc5){
    int idx = blockIdx.x*256 + threadIdx.x;        // 4*1280
    if (idx >= 4*1280) return;
    int n = idx % 1280, l = idx / 1280;
    const float* B = kqv_b + l*768;
    float val, scl = 1.f;
    if (n < 256) val = B[256+n];
    else {
        int g = (n-256) >> 8;
        int r = g & 1, isv = g >> 1;
        int c = (n-256) & 255;
        int h = c >> 5, f = c & 31;
        const float* Rm = (isv ? vrel : krel) + ((size_t)l*2 + r)*8192 + h*1024;
        int base = isv ? 512 : 0;
        float a = 0.f;
        for (int d=0; d<32; ++d) a += B[base + h*32 + d] * Rm[d*32 + f];
        val = a;
        if (!isv) scl = prel[l*16 + r*8 + h] * 0.17677669529663687f;
    }
    bias5[idx] = val;
    sc5[idx] = scl;
}
// out_w [l][k][n] fp32 -> Wto k-panels [l][kpanel][n][32k] bf16
__global__ void build_wo_k(const float* __restrict__ out_w, u16* __restrict__ Wto){
    int idx = blockIdx.x*256 + threadIdx.x;        // 4*256*256
    int k = idx & 255;
    int n = (idx >> 8) & 255;
    int l = idx >> 16;
    Wto[(size_t)l*65536 + (size_t)(k>>5)*OPAN + n*32 + (k&31)] =
        f2bf(out_w[(size_t)l*65536 + k*256 + n]);
}
// x fp32 row-major -> xbf bf16 k-panels [kpanel][row][32k]
__global__ void cvt_x_k(const float* __restrict__ x, u16* __restrict__ xbf){
    int idx = blockIdx.x*256 + threadIdx.x;        // 640000 (8 elems each)
    int e = idx*8;
    int row = e >> 8, col = e & 255;
    const float4* xp = (const float4*)x;
    float4 a = xp[(size_t)idx*2], b = xp[(size_t)idx*2+1];
    uint4 o;
    o.x = (unsigned)f2bf(a.x) | ((unsigned)f2bf(a.y)<<16);
    o.y = (unsigned)f2bf(a.z) | ((unsigned)f2bf(a.w)<<16);
    o.z = (unsigned)f2bf(b.x) | ((unsigned)f2bf(b.y)<<16);
    o.w = (unsigned)f2bf(b.z) | ((unsigned)f2bf(b.w)<<16);
    *(uint4*)&xbf[(size_t)(col>>5)*APAN + (size_t)row*32 + (col&31)] = o;
}

// ======================= K1: 5-output MFMA GEMM (panel-staged, XCD-clustered) =========
// kvb byte-rows [rel*NN+node][512]: kr 256xfp8 (prel/sqrt folded) || vr 256xfp8
__global__ __launch_bounds__(256) void gemm5_k(const u16* __restrict__ A,
        const u16* __restrict__ Wt, const float* __restrict__ biasp,
        const float* __restrict__ sc5p,
        u16* __restrict__ qb, u8* __restrict__ kvb){
    int L = blockIdx.x;
    int xcd = L & 7;
    int t = L >> 3;                  // 0..199
    int ytile = xcd*20 + t/10;       // 0..159
    int xtile = t % 10;
    if (ytile >= 157) return;        // uniform per block (before any barrier)
    int col0 = xtile * 128;
    int row0 = ytile * 128;

    __shared__ __align__(16) char smem[33792];   // max(As+Bs=16K, Cs=128*66*4)
    u16* As = (u16*)smem;                        // 4096 u16
    u16* Bs = (u16*)(smem + 8192);               // 4096 u16
    float* Cs = (float*)smem;                    // 128*66 (aliases As/Bs post-K-loop)
    int tid = threadIdx.x;
    int w = tid >> 6, lane = tid & 63;
    int wm = w & 1, wn = w >> 1;
    f32x4 acc[4][4];
    #pragma unroll
    for (int i=0;i<4;++i)
        #pragma unroll
        for (int j=0;j<4;++j) acc[i][j] = (f32x4){0.f,0.f,0.f,0.f};

    int lm = lane & 15, quad = lane >> 4;
    int kq0 = quad ^ (lm & 3);
    int aoff = (wm*64 + lm)*32 + kq0*8;
    int boff = (wn*64 + lm)*32 + kq0*8;

    for (int kk = 0; kk < 8; ++kk){
        #pragma unroll
        for (int it = 0; it < 2; ++it){
            int s = w*128 + it*64 + lane;      // 16B slot id (0..511)
            int row = s >> 2, q0 = s & 3;
            int kq = q0 ^ (row & 3);           // write-side swizzle via source addr
            gload_lds16(&A [(size_t)kk*APAN + (size_t)(row0+row)*32 + kq*8], &As[(size_t)(w*128 + it*64)*8]);
            gload_lds16(&Wt[(size_t)kk*BPAN + (size_t)(col0+row)*32 + kq*8], &Bs[(size_t)(w*128 + it*64)*8]);
        }
        __syncthreads();
        bf16x8 af[4], bfr[4];
        #pragma unroll
        for (int mi=0; mi<4; ++mi) af[mi]  = *(bf16x8*)&As[aoff + mi*512];
        #pragma unroll
        for (int ni=0; ni<4; ++ni) bfr[ni] = *(bf16x8*)&Bs[boff + ni*512];
        #pragma unroll
        for (int mi=0; mi<4; ++mi)
            #pragma unroll
            for (int ni=0; ni<4; ++ni)
                acc[mi][ni] = __builtin_amdgcn_mfma_f32_16x16x32_bf16(af[mi], bfr[ni], acc[mi][ni], 0,0,0);
        __syncthreads();    // last iteration also fences As/Bs before Cs aliasing
    }

    int bufi = col0 >> 8;   // 0:q 1:kr0 2:kr1 3:vr0 4:vr1 (uniform per block)
    int cbase = col0 & 255;
    float bvv[4], scv[4];
    #pragma unroll
    for (int ni=0; ni<4; ++ni){
        bvv[ni] = biasp[col0 + wn*64 + ni*16 + lm];
        scv[ni] = sc5p [col0 + wn*64 + ni*16 + lm];
    }

    int rowl_s = tid >> 3;              // 0..31
    int col8   = tid & 7;               // 0..7 (8 lcols each)
    int gcb    = (col8 >> 2)*64 + (col8 & 3)*8;

    #pragma unroll
    for (int p=0; p<2; ++p){
        if (p) __syncthreads();
        #pragma unroll
        for (int nj=0; nj<2; ++nj){
            int ni = p*2 + nj;
            int lcol = wn*32 + nj*16 + lm;
            #pragma unroll
            for (int mi=0; mi<4; ++mi){
                #pragma unroll
                for (int t2=0; t2<4; ++t2){
                    int lr = wm*64 + mi*16 + quad*4 + t2;
                    Cs[lr*66 + lcol] = (acc[mi][ni][t2] + bvv[ni]) * scv[ni];
                }
            }
        }
        __syncthreads();
        int cw = cbase + gcb + p*32;
        #pragma unroll
        for (int it=0; it<4; ++it){
            int rl = rowl_s + it*32;
            int r = row0 + rl;
            if (r < NN){
                const float* src = &Cs[rl*66 + col8*8];
                float cf[8];
                *(float4*)&cf[0] = *(const float4*)&src[0];
                *(float4*)&cf[4] = *(const float4*)&src[4];
                if (bufi == 0){
                    uint4 o;
                    o.x = (unsigned)f2bf(cf[0]) | ((unsigned)f2bf(cf[1])<<16);
                    o.y = (unsigned)f2bf(cf[2]) | ((unsigned)f2bf(cf[3])<<16);
                    o.z = (unsigned)f2bf(cf[4]) | ((unsigned)f2bf(cf[5])<<16);
                    o.w = (unsigned)f2bf(cf[6]) | ((unsigned)f2bf(cf[7])<<16);
                    *(uint4*)&qb[(size_t)r*256 + cw] = o;
                } else if (bufi <= 2){
                    int rel = bufi - 1;
                    uint2 o = enc8_fp8(cf);
                    *(uint2*)&kvb[(size_t)(rel*NN + r)*KVSTRIDE + cw] = o;
                } else {
                    int rel = bufi - 3;
                    uint2 o = enc8_fp8(cf);
                    *(uint2*)&kvb[(size_t)(rel*NN + r)*KVSTRIDE + 256 + cw] = o;
                }
            }
        }
    }
}

// ======================= K2: split-wave CSR attention, online softmax ==============
// kv row: kr fp8 (prel-scaled) + vr fp8 -> 512 B/edge gathered.
// A2 output in k-panel layout (A operand of gemmOln/gemmO)
__global__ __launch_bounds__(256) void attn_k(const u16* __restrict__ qb,
        const u8* __restrict__ kvb,
        const int* __restrict__ row_ptr, const int* __restrict__ epk,
        u16* __restrict__ A2){
    int wv = threadIdx.x >> 6, lane = threadIdx.x & 63;
    int node = blockIdx.x*4 + wv;
    int l32 = lane & 31;
    int half = lane >> 5;
    int start = row_ptr[node], end = row_ptr[node+1];
    float qf[8];
    {
        uint4 qr = *(const uint4*)&qb[(size_t)node*256 + l32*8];
        dec8(qr, qf);
    }
    float m = -1e30f, s = 0.f;
    float acc[8] = {0.f,0.f,0.f,0.f,0.f,0.f,0.f,0.f};

    int i0 = start + half;
    uint2 k0={0,0}, k1={0,0}, v0={0,0}, v1={0,0};
    if (i0 < end){
        const u8* row = &kvb[(size_t)epk[i0]*KVSTRIDE];
        k0 = *(const uint2*)(row + l32*8);
        v0 = *(const uint2*)(row + 256 + l32*8);
    }
    if (i0 + 2 < end){
        const u8* row = &kvb[(size_t)epk[i0+2]*KVSTRIDE];
        k1 = *(const uint2*)(row + l32*8);
        v1 = *(const uint2*)(row + 256 + l32*8);
    }
    int pk = (i0 + 4 < end) ? epk[i0+4] : 0;

    for (int i = i0; i < end; i += 2){
        uint2 kc = k0, vc = v0;
        k0 = k1; v0 = v1;
        if (i + 4 < end){                      // refill depth-2 slot
            const u8* row = &kvb[(size_t)pk*KVSTRIDE];
            k1 = *(const uint2*)(row + l32*8);
            v1 = *(const uint2*)(row + 256 + l32*8);
        }
        if (i + 6 < end) pk = epk[i+6];        // index 3 deep
        float kv[8];
        dec8_fp8(kc, kv);
        float p = dot8(qf, kv);
        p += __shfl_xor(p, 1);
        p += __shfl_xor(p, 2);                 // logit (prel/sqrt folded into kr)
        float mo = m;
        m = fmaxf(m, p);
        float sc = __expf(mo - m);
        float pe = __expf(p - m);
        s = s*sc + pe;
        float vv[8];
        dec8_fp8(vc, vv);
        #pragma unroll
        for (int j=0;j<8;++j) acc[j] = acc[j]*sc + pe*vv[j];
    }
    // merge the two halves' online-softmax states (m=-1e30: no inf-inf NaN)
    float mO = __shfl_xor(m, 32);
    float mA = fmaxf(m, mO);
    float eS = __expf(m - mA);
    float sh = s * eS;
    float sA = sh + __shfl_xor(sh, 32);
    float rs = 1.f / fmaxf(sA, 1e-16f);
    float oA[8];
    #pragma unroll
    for (int j=0;j<8;++j){
        float a = acc[j] * eS;
        oA[j] = a + __shfl_xor(a, 32);
    }
    if (half == 0){
        u16 o[8];
        #pragma unroll
        for (int j=0;j<8;++j) o[j] = f2bf(gelu_exact(oA[j]*rs));
        uint4 ov;
        ov.x = (unsigned)o[0] | ((unsigned)o[1]<<16);
        ov.y = (unsigned)o[2] | ((unsigned)o[3]<<16);
        ov.z = (unsigned)o[4] | ((unsigned)o[5]<<16);
        ov.w = (unsigned)o[6] | ((unsigned)o[7]<<16);
        int c0 = l32*8;
        *(uint4*)&A2[(size_t)(c0>>5)*APAN + (size_t)node*32 + (c0&31)] = ov;
    }
}

// ======================= K3a: out GEMM + skip + relu + LN (layers 0-2) ===========
// A2 and Wto in k-panel layout -> contiguous staging runs.
// emits h_out fp32 (row-major) and hbf bf16 k-panels for next gemm5
__global__ __launch_bounds__(256) void gemmOln_k(const u16* __restrict__ A,
        const u16* __restrict__ Wt, const float* __restrict__ bias,
        const float* __restrict__ h_in, const float* __restrict__ skip_l,
        const float* __restrict__ g, const float* __restrict__ b,
        float* __restrict__ h_out, u16* __restrict__ hbf){
    __shared__ u16 As[2048];          // 64 rows x 32 k
    __shared__ u16 Bs[8192];          // 256 cols x 32 k
    __shared__ float part_s[64*33];
    __shared__ float part_q[64*33];
    __shared__ float mu_s[64], rstd_s[64];
    int tid = threadIdx.x;
    int w = tid >> 6, lane = tid & 63;
    int row0 = blockIdx.x * 64;
    int wm = w & 1, wn = w >> 1;
    f32x4 acc[2][8];
    #pragma unroll
    for (int i=0;i<2;++i)
        #pragma unroll
        for (int j=0;j<8;++j) acc[i][j] = (f32x4){0.f,0.f,0.f,0.f};

    int lm = lane & 15, quad = lane >> 4;
    int kq0 = quad ^ (lm & 3);
    int aoff = (wm*32 + lm)*32 + kq0*8;
    int boff = (wn*128 + lm)*32 + kq0*8;

    for (int kk = 0; kk < 8; ++kk){
        {
            int s = tid;                       // 256 slots = 64 rows x 4
            int row = s >> 2, q0 = s & 3;
            int kq = q0 ^ (row & 3);
            gload_lds16(&A[(size_t)kk*APAN + (size_t)(row0+row)*32 + kq*8], &As[(size_t)(w*64)*8]);
        }
        #pragma unroll
        for (int it = 0; it < 4; ++it){        // 1024 slots = 256 n-rows x 4
            int s = it*256 + w*64 + lane;
            int row = s >> 2, q0 = s & 3;
            int kq = q0 ^ (row & 3);
            gload_lds16(&Wt[(size_t)kk*OPAN + (size_t)row*32 + kq*8], &Bs[(size_t)(it*256 + w*64)*8]);
        }
        __syncthreads();
        bf16x8 af[2], bfr[8];
        #pragma unroll
        for (int mi=0; mi<2; ++mi) af[mi]  = *(bf16x8*)&As[aoff + mi*512];
        #pragma unroll
        for (int ni=0; ni<8; ++ni) bfr[ni] = *(bf16x8*)&Bs[boff + ni*512];
        #pragma unroll
        for (int mi=0; mi<2; ++mi)
            #pragma unroll
            for (int ni=0; ni<8; ++ni)
                acc[mi][ni] = __builtin_amdgcn_mfma_f32_16x16x32_bf16(af[mi], bfr[ni], acc[mi][ni], 0,0,0);
        __syncthreads();
    }

    float sskip = 1.f/(1.f+__expf(-skip_l[0]));
    float osk = 1.f - sskip;
    float bv[8], gv[8], bbv[8];
    #pragma unroll
    for (int ni=0; ni<8; ++ni){
        int colg = wn*128 + ni*16 + lm;
        bv[ni]  = bias[colg];
        gv[ni]  = g[colg];
        bbv[ni] = b[colg];
    }
    #pragma unroll
    for (int mi=0; mi<2; ++mi){
        #pragma unroll
        for (int t=0; t<4; ++t){
            int lr = wm*32 + mi*16 + quad*4 + t;
            int r = row0 + lr;
            float ps = 0.f, pq = 0.f;
            #pragma unroll
            for (int ni=0; ni<8; ++ni){
                int colg = wn*128 + ni*16 + lm;
                float hv = (r < NN) ? h_in[(size_t)r*256 + colg] : 0.f;
                float val = sskip*(acc[mi][ni][t] + bv[ni]) + osk*hv;
                val = fmaxf(val, 0.f);
                acc[mi][ni][t] = val;
                ps += val; pq += val*val;
            }
            part_s[lr*33 + wn*16 + lm] = ps;
            part_q[lr*33 + wn*16 + lm] = pq;
        }
    }
    __syncthreads();
    if (tid < 64){
        float S = 0.f, Q = 0.f;
        #pragma unroll 8
        for (int t2=0; t2<32; ++t2){
            S += part_s[tid*33 + t2];
            Q += part_q[tid*33 + t2];
        }
        float mu = S * (1.f/256.f);
        float var = Q * (1.f/256.f) - mu*mu;
        mu_s[tid] = mu;
        rstd_s[tid] = rsqrtf(var + 1e-5f);
    }
    __syncthreads();
    #pragma unroll
    for (int mi=0; mi<2; ++mi){
        #pragma unroll
        for (int t=0; t<4; ++t){
            int lr = wm*32 + mi*16 + quad*4 + t;
            int r = row0 + lr;
            if (r >= NN) continue;
            float mu = mu_s[lr], rstd = rstd_s[lr];
            #pragma unroll
            for (int ni=0; ni<8; ++ni){
                int colg = wn*128 + ni*16 + lm;
                float o = (acc[mi][ni][t] - mu)*rstd*gv[ni] + bbv[ni];
                h_out[(size_t)r*256 + colg] = o;
                hbf[(size_t)(colg>>5)*APAN + (size_t)r*32 + (colg&31)] = f2bf(o);
            }
        }
    }
}

// ======================= K3b: out GEMM + skip blend (final layer) =======================
// A2 and Wto in k-panel layout
__global__ __launch_bounds__(256) void gemmO_k(const u16* __restrict__ A,
        const u16* __restrict__ Wt, const float* __restrict__ bias,
        const float* __restrict__ h_in, const float* __restrict__ skip_l,
        float* __restrict__ outp){
    __shared__ u16 As[4096];
    __shared__ u16 Bs[4096];
    int tid = threadIdx.x;
    int w = tid >> 6, lane = tid & 63;
    int row0 = blockIdx.x * 128;
    int col0 = blockIdx.y * 128;
    int wm = w & 1, wn = w >> 1;
    f32x4 acc[4][4];
    #pragma unroll
    for (int i=0;i<4;++i)
        #pragma unroll
        for (int j=0;j<4;++j) acc[i][j] = (f32x4){0.f,0.f,0.f,0.f};

    int lm = lane & 15, quad = lane >> 4;
    int kq0 = quad ^ (lm & 3);
    int aoff = (wm*64 + lm)*32 + kq0*8;
    int boff = (wn*64 + lm)*32 + kq0*8;

    for (int kk = 0; kk < 8; ++kk){
        #pragma unroll
        for (int it = 0; it < 2; ++it){
            int s = w*128 + it*64 + lane;
            int row = s >> 2, q0 = s & 3;
            int kq = q0 ^ (row & 3);
            gload_lds16(&A [(size_t)kk*APAN + (size_t)(row0+row)*32 + kq*8], &As[(size_t)(w*128 + it*64)*8]);
            gload_lds16(&Wt[(size_t)kk*OPAN + (size_t)(col0+row)*32 + kq*8], &Bs[(size_t)(w*128 + it*64)*8]);
        }
        __syncthreads();
        bf16x8 af[4], bfr[4];
        #pragma unroll
        for (int mi=0; mi<4; ++mi) af[mi]  = *(bf16x8*)&As[aoff + mi*512];
        #pragma unroll
        for (int ni=0; ni<4; ++ni) bfr[ni] = *(bf16x8*)&Bs[boff + ni*512];
        #pragma unroll
        for (int mi=0; mi<4; ++mi)
            #pragma unroll
            for (int ni=0; ni<4; ++ni)
                acc[mi][ni] = __builtin_amdgcn_mfma_f32_16x16x32_bf16(af[mi], bfr[ni], acc[mi][ni], 0,0,0);
        __syncthreads();
    }
    float s = 1.f/(1.f+expf(-skip_l[0]));
    float os = 1.f - s;
    #pragma unroll
    for (int ni=0; ni<4; ++ni){
        int colg = col0 + wn*64 + ni*16 + lm;
        float bv = bias[colg];
        #pragma unroll
        for (int mi=0; mi<4; ++mi){
            #pragma unroll
            for (int t=0; t<4; ++t){
                int r = row0 + wm*64 + mi*16 + quad*4 + t;
                if (r < NN)
                    outp[(size_t)r*256 + colg] =
                        s*(acc[mi][ni][t] + bv) + os*h_in[(size_t)r*256 + colg];
            }
        }
    }
}

// ======================= host =======================
extern "C" void kernel_launch(void* const* d_in, const int* in_sizes, int n_in,
                              void* d_out, int out_size, void* d_ws, size_t ws_size,
                              hipStream_t stream){
    (void)in_sizes; (void)n_in; (void)out_size; (void)ws_size;
    const float* x     = (const float*)d_in[0];
    const int*   ei0   = (const int*)d_in[1];
    const int*   ei1   = (const int*)d_in[2];
    const float* kqv_w = (const float*)d_in[3];
    const float* kqv_b = (const float*)d_in[4];
    const float* out_w = (const float*)d_in[5];
    const float* out_b = (const float*)d_in[6];
    const float* skip  = (const float*)d_in[7];
    const float* krel  = (const float*)d_in[8];
    const float* vrel  = (const float*)d_in[9];
    const float* prel  = (const float*)d_in[10];
    const float* ln_g  = (const float*)d_in[11];
    const float* ln_b  = (const float*)d_in[12];
    float* outp = (float*)d_out;

    char* wp = (char*)d_ws;
    auto alloc = [&](size_t bytes)->void*{
        void* p = wp; wp += (bytes + 255) & ~(size_t)255; return p;
    };
    float* hA    = (float*)alloc((size_t)NN*CC*4);
    float* hB    = (float*)alloc((size_t)NN*CC*4);
    u16*   xbf   = (u16*)alloc((size_t)NPAD*CC*2);   // k-panel layout
    u16*   hbf   = (u16*)alloc((size_t)NPAD*CC*2);   // k-panel layout
    u16*   A2    = (u16*)alloc((size_t)NPAD*CC*2);   // k-panel layout
    u16*   qb    = (u16*)alloc((size_t)NN*CC*2);
    u8*    kvb   = (u8*)alloc((size_t)2*NN*KVSTRIDE);   // [rel*NN+node][kr fp8 || vr fp8]
    u16*   Wt5   = (u16*)alloc((size_t)4*1280*256*2);   // k-panel layout
    u16*   Wto   = (u16*)alloc((size_t)4*256*256*2);    // k-panel layout
    float* bias5 = (float*)alloc((size_t)4*1280*4);
    float* sc5   = (float*)alloc((size_t)4*1280*4);
    int* cnt     = (int*)alloc((size_t)NN*4);      // cnt+cursor adjacent: one memset
    int* cursor  = (int*)alloc((size_t)NN*4);
    int* incl    = (int*)alloc((size_t)NN*4);
    int* row_ptr = (int*)alloc((size_t)(NN+1)*4);
    int* bsum    = (int*)alloc(128*4);
    int* epk     = (int*)alloc((size_t)TE*4);

    // prep (weights + input cast) — independent of CSR chain
    build_w5_k<<<5120,256,0,stream>>>(kqv_w, krel, vrel, Wt5);
    build_bias5_k<<<20,256,0,stream>>>(kqv_b, krel, vrel, prel, bias5, sc5);
    build_wo_k<<<1024,256,0,stream>>>(out_w, Wto);
    cvt_x_k<<<2500,256,0,stream>>>(x, xbf);

    // CSR build
    size_t cntBlk = ((size_t)NN*4 + 255) & ~(size_t)255;
    hipMemsetAsync(cnt, 0, cntBlk + (size_t)NN*4, stream);   // zero cnt AND cursor
    hist_k<<<1250,256,0,stream>>>(ei0, ei1, cnt);
    scan_block_k<<<79,256,0,stream>>>(cnt, incl, bsum);
    scan_bsum_k<<<1,128,0,stream>>>(bsum, 79);
    finalize_rowptr_k<<<79,256,0,stream>>>(cnt, incl, bsum, row_ptr);
    scatter_k<<<1250,256,0,stream>>>(ei0, ei1, row_ptr, cursor, epk);

    const float* h_in = x;
    const u16*   Ain  = xbf;
    float* houts[4] = {hA, hB, hA, outp};
    for (int l=0; l<4; ++l){
        gemm5_k<<<1600,256,0,stream>>>(Ain, Wt5 + (size_t)l*327680,
                bias5 + l*1280, sc5 + l*1280, qb, kvb);
        attn_k<<<5000,256,0,stream>>>(qb, kvb, row_ptr, epk, A2);
        if (l < 3){
            gemmOln_k<<<314,256,0,stream>>>(A2, Wto + (size_t)l*65536,
                    out_b + l*256, h_in, skip + l, ln_g + l*256, ln_b + l*256,
                    houts[l], hbf);
        } else {
            gemmO_k<<<dim3(157,2),256,0,stream>>>(A2, Wto + (size_t)l*65536,
                    out_b + l*256, h_in, skip + l, outp);
        }
        h_in = houts[l];
        Ain = hbf;
    }
}

// Round 16
// 480.269 us; speedup vs baseline: 1.1434x; 1.0375x over previous
//
#include <hip/hip_runtime.h>
#include <math.h>

#define NN 20000
#define NPAD 20096          // padded rows for unguarded MFMA staging (157*128)
#define CC 256
#define HH 8
#define EE 160000
#define TE 320000
#define KVSTRIDE 512        // bytes per kv row: kr 256xfp8 (256B) + vr 256xfp8 (256B)
#define APAN ((size_t)NPAD*32)   // u16 elems per A-operand k-panel (xbf/hbf/A2)
#define BPAN 40960               // u16 elems per Wt5 k-panel (1280*32)
#define OPAN 8192                // u16 elems per Wto k-panel (256*32)

typedef unsigned short u16;
typedef unsigned char u8;
typedef __attribute__((ext_vector_type(8))) short bf16x8;
typedef __attribute__((ext_vector_type(4))) float f32x4;
typedef __attribute__((ext_vector_type(2))) float f32x2;

__device__ __forceinline__ float gelu_exact(float x){
    return 0.5f*x*(1.0f+erff(x*0.7071067811865476f));
}
__device__ __forceinline__ u16 f2bf(float f){
    unsigned u = __float_as_uint(f);
    unsigned r = (u + 0x7fffu + ((u >> 16) & 1u)) >> 16;
    return (u16)r;
}
__device__ __forceinline__ float bf2f(u16 s){
    return __uint_as_float(((unsigned)s) << 16);
}
__device__ __forceinline__ void dec8(uint4 u, float* f){
    f[0]=__uint_as_float(u.x<<16); f[1]=__uint_as_float(u.x&0xffff0000u);
    f[2]=__uint_as_float(u.y<<16); f[3]=__uint_as_float(u.y&0xffff0000u);
    f[4]=__uint_as_float(u.z<<16); f[5]=__uint_as_float(u.z&0xffff0000u);
    f[6]=__uint_as_float(u.w<<16); f[7]=__uint_as_float(u.w&0xffff0000u);
}
__device__ __forceinline__ void dec8_fp8(uint2 u, float* f){
    f32x2 a = __builtin_amdgcn_cvt_pk_f32_fp8(u.x, false);
    f32x2 b = __builtin_amdgcn_cvt_pk_f32_fp8(u.x, true);
    f32x2 c = __builtin_amdgcn_cvt_pk_f32_fp8(u.y, false);
    f32x2 d = __builtin_amdgcn_cvt_pk_f32_fp8(u.y, true);
    f[0]=a.x; f[1]=a.y; f[2]=b.x; f[3]=b.y;
    f[4]=c.x; f[5]=c.y; f[6]=d.x; f[7]=d.y;
}
__device__ __forceinline__ uint2 enc8_fp8(const float* f){
    int t0 = __builtin_amdgcn_cvt_pk_fp8_f32(f[0], f[1], 0, false);
    t0     = __builtin_amdgcn_cvt_pk_fp8_f32(f[2], f[3], t0, true);
    int t1 = __builtin_amdgcn_cvt_pk_fp8_f32(f[4], f[5], 0, false);
    t1     = __builtin_amdgcn_cvt_pk_fp8_f32(f[6], f[7], t1, true);
    uint2 r; r.x = (unsigned)t0; r.y = (unsigned)t1;
    return r;
}
__device__ __forceinline__ float dot8(const float* a, const float* b){
    return a[0]*b[0]+a[1]*b[1]+a[2]*b[2]+a[3]*b[3]
          +a[4]*b[4]+a[5]*b[5]+a[6]*b[6]+a[7]*b[7];
}
__device__ __forceinline__ void gload_lds16(const u16* gsrc, u16* lds_dst){
    __builtin_amdgcn_global_load_lds((const __attribute__((address_space(1))) unsigned int*)gsrc,
                                     (__attribute__((address_space(3))) unsigned int*)lds_dst,
                                     16, 0, 0);
}

// ======================= CSR build =======================
__global__ void hist_k(const int* __restrict__ ei0, const int* __restrict__ ei1,
                       int* __restrict__ cnt){
    int e = blockIdx.x*256 + threadIdx.x;
    if (e < TE){
        int dst = (e < EE) ? ei0[EE + e] : ei1[EE + (e - EE)];
        atomicAdd(&cnt[dst], 1);
    }
}
__global__ void scan_block_k(const int* __restrict__ cnt, int* __restrict__ incl,
                             int* __restrict__ bsum){
    __shared__ int tmp[256];
    int tid = threadIdx.x;
    int i = blockIdx.x*256 + tid;
    int v = (i < NN) ? cnt[i] : 0;
    tmp[tid] = v;
    __syncthreads();
    for (int d=1; d<256; d<<=1){
        int t = (tid>=d) ? tmp[tid-d] : 0;
        __syncthreads();
        tmp[tid] += t;
        __syncthreads();
    }
    if (i < NN) incl[i] = tmp[tid];
    if (tid == 255) bsum[blockIdx.x] = tmp[255];
}
__global__ void scan_bsum_k(int* bsum, int nb){
    __shared__ int tmp[128];
    int tid = threadIdx.x;
    int v = (tid < nb) ? bsum[tid] : 0;
    tmp[tid] = v;
    __syncthreads();
    for (int d=1; d<128; d<<=1){
        int t = (tid>=d) ? tmp[tid-d] : 0;
        __syncthreads();
        tmp[tid] += t;
        __syncthreads();
    }
    if (tid < nb) bsum[tid] = tmp[tid] - v;   // exclusive
}
__global__ void finalize_rowptr_k(const int* __restrict__ cnt, const int* __restrict__ incl,
                                  const int* __restrict__ bsum, int* __restrict__ row_ptr){
    int i = blockIdx.x*256 + threadIdx.x;
    if (i < NN) row_ptr[i] = incl[i] - cnt[i] + bsum[blockIdx.x];
    if (i == NN) row_ptr[NN] = TE;
}
// stores the final kv-row index rel*NN+src per CSR slot
__global__ void scatter_k(const int* __restrict__ ei0, const int* __restrict__ ei1,
                          const int* __restrict__ row_ptr, int* __restrict__ cursor,
                          int* __restrict__ epk){
    int e = blockIdx.x*256 + threadIdx.x;
    if (e < TE){
        int src, dst, rel;
        if (e < EE){ src = ei0[e]; dst = ei0[EE+e]; rel = 0; }
        else { int ee=e-EE; src = ei1[ee]; dst = ei1[EE+ee]; rel = 1; }
        int pos = atomicAdd(&cursor[dst], 1);
        epk[row_ptr[dst] + pos] = rel*NN + src;
    }
}

// ======================= fused weight/input prep (one dispatch) =======================
// blocks [0,5120): Wt5 k-panels; [5120,7620): cvt x->xbf panels;
// [7620,8644): Wto k-panels; [8644,8664): bias5+sc5
__global__ void prep_k(const float* __restrict__ kqv_w, const float* __restrict__ kqv_b,
                       const float* __restrict__ krel, const float* __restrict__ vrel,
                       const float* __restrict__ prel, const float* __restrict__ out_w,
                       const float* __restrict__ x,
                       u16* __restrict__ Wt, u16* __restrict__ xbf, u16* __restrict__ Wto,
                       float* __restrict__ bias5, float* __restrict__ sc5){
    int b = blockIdx.x;
    if (b < 5120){
        int idx = b*256 + threadIdx.x;                 // 4*1280*256
        int k = idx & 255;
        int n = (idx >> 8) % 1280;
        int l = idx / (1280*256);
        const float* W = kqv_w + (size_t)l*196608;     // [256][768]
        float val;
        if (n < 256){
            val = W[k*768 + 256 + n];
        } else {
            int g = (n-256) >> 8;
            int r = g & 1, isv = g >> 1;
            int c = (n-256) & 255;
            int h = c >> 5, f = c & 31;
            const float* Rm = (isv ? vrel : krel) + ((size_t)l*2 + r)*8192 + h*1024;
            int base = isv ? 512 : 0;
            float a = 0.f;
            #pragma unroll 8
            for (int d=0; d<32; ++d)
                a += W[k*768 + base + h*32 + d] * Rm[d*32 + f];
            val = a;
        }
        Wt[(size_t)l*327680 + (size_t)(k>>5)*BPAN + n*32 + (k&31)] = f2bf(val);
    } else if (b < 7620){
        int idx = (b-5120)*256 + threadIdx.x;          // 640000 (8 elems each)
        int e = idx*8;
        int row = e >> 8, col = e & 255;
        const float4* xp = (const float4*)x;
        float4 a = xp[(size_t)idx*2], bb = xp[(size_t)idx*2+1];
        uint4 o;
        o.x = (unsigned)f2bf(a.x) | ((unsigned)f2bf(a.y)<<16);
        o.y = (unsigned)f2bf(a.z) | ((unsigned)f2bf(a.w)<<16);
        o.z = (unsigned)f2bf(bb.x) | ((unsigned)f2bf(bb.y)<<16);
        o.w = (unsigned)f2bf(bb.z) | ((unsigned)f2bf(bb.w)<<16);
        *(uint4*)&xbf[(size_t)(col>>5)*APAN + (size_t)row*32 + (col&31)] = o;
    } else if (b < 8644){
        int idx = (b-7620)*256 + threadIdx.x;          // 4*256*256
        int k = idx & 255;
        int n = (idx >> 8) & 255;
        int l = idx >> 16;
        Wto[(size_t)l*65536 + (size_t)(k>>5)*OPAN + n*32 + (k&31)] =
            f2bf(out_w[(size_t)l*65536 + k*256 + n]);
    } else {
        int idx = (b-8644)*256 + threadIdx.x;          // 4*1280
        if (idx >= 4*1280) return;
        int n = idx % 1280, l = idx / 1280;
        const float* B = kqv_b + l*768;
        float val, scl = 1.f;
        if (n < 256) val = B[256+n];
        else {
            int g = (n-256) >> 8;
            int r = g & 1, isv = g >> 1;
            int c = (n-256) & 255;
            int h = c >> 5, f = c & 31;
            const float* Rm = (isv ? vrel : krel) + ((size_t)l*2 + r)*8192 + h*1024;
            int base = isv ? 512 : 0;
            float a = 0.f;
            for (int d=0; d<32; ++d) a += B[base + h*32 + d] * Rm[d*32 + f];
            val = a;
            if (!isv) scl = prel[l*16 + r*8 + h] * 0.17677669529663687f;
        }
        bias5[idx] = val;
        sc5[idx] = scl;
    }
}

// ======================= K1: 5-output MFMA GEMM (BK=64, XCD-clustered) =========
// BK=64: two 32-k panels staged per iteration -> 4 barrier pairs instead of 8
// (the measured stall was the per-iteration vmcnt(0)+barrier drain).
// LDS: As 16KB + Bs 16KB staged; Cs (33.8KB) aliases both post-K-loop.
__global__ __launch_bounds__(256) void gemm5_k(const u16* __restrict__ A,
        const u16* __restrict__ Wt, const float* __restrict__ biasp,
        const float* __restrict__ sc5p,
        u16* __restrict__ qb, u8* __restrict__ kvb){
    int L = blockIdx.x;
    int xcd = L & 7;
    int t = L >> 3;                  // 0..199
    int ytile = xcd*20 + t/10;       // 0..159
    int xtile = t % 10;
    if (ytile >= 157) return;        // uniform per block (before any barrier)
    int col0 = xtile * 128;
    int row0 = ytile * 128;

    __shared__ __align__(16) char smem[33792];   // max(As+Bs=32K, Cs=128*66*4)
    u16* As = (u16*)smem;                        // 8192 u16 (2 panels of 4096)
    u16* Bs = (u16*)(smem + 16384);              // 8192 u16
    float* Cs = (float*)smem;                    // 128*66 (aliases As/Bs post-K-loop)
    int tid = threadIdx.x;
    int w = tid >> 6, lane = tid & 63;
    int wm = w & 1, wn = w >> 1;
    f32x4 acc[4][4];
    #pragma unroll
    for (int i=0;i<4;++i)
        #pragma unroll
        for (int j=0;j<4;++j) acc[i][j] = (f32x4){0.f,0.f,0.f,0.f};

    int lm = lane & 15, quad = lane >> 4;
    int kq0 = quad ^ (lm & 3);
    int aoff = (wm*64 + lm)*32 + kq0*8;
    int boff = (wn*64 + lm)*32 + kq0*8;

    for (int kk = 0; kk < 4; ++kk){
        #pragma unroll
        for (int hf = 0; hf < 2; ++hf){
            int pan = kk*2 + hf;
            #pragma unroll
            for (int it = 0; it < 2; ++it){
                int s = w*128 + it*64 + lane;      // 16B slot id (0..511)
                int row = s >> 2, q0 = s & 3;
                int kq = q0 ^ (row & 3);           // write-side swizzle via source addr
                gload_lds16(&A [(size_t)pan*APAN + (size_t)(row0+row)*32 + kq*8],
                            &As[(size_t)(hf*4096) + (size_t)(w*128 + it*64)*8]);
                gload_lds16(&Wt[(size_t)pan*BPAN + (size_t)(col0+row)*32 + kq*8],
                            &Bs[(size_t)(hf*4096) + (size_t)(w*128 + it*64)*8]);
            }
        }
        __syncthreads();
        #pragma unroll
        for (int hf = 0; hf < 2; ++hf){
            bf16x8 af[4], bfr[4];
            #pragma unroll
            for (int mi=0; mi<4; ++mi) af[mi]  = *(bf16x8*)&As[hf*4096 + aoff + mi*512];
            #pragma unroll
            for (int ni=0; ni<4; ++ni) bfr[ni] = *(bf16x8*)&Bs[hf*4096 + boff + ni*512];
            #pragma unroll
            for (int mi=0; mi<4; ++mi)
                #pragma unroll
                for (int ni=0; ni<4; ++ni)
                    acc[mi][ni] = __builtin_amdgcn_mfma_f32_16x16x32_bf16(af[mi], bfr[ni], acc[mi][ni], 0,0,0);
        }
        __syncthreads();    // last iteration also fences As/Bs before Cs aliasing
    }

    int bufi = col0 >> 8;   // 0:q 1:kr0 2:kr1 3:vr0 4:vr1 (uniform per block)
    int cbase = col0 & 255;
    float bvv[4], scv[4];
    #pragma unroll
    for (int ni=0; ni<4; ++ni){
        bvv[ni] = biasp[col0 + wn*64 + ni*16 + lm];
        scv[ni] = sc5p [col0 + wn*64 + ni*16 + lm];
    }

    int rowl_s = tid >> 3;              // 0..31
    int col8   = tid & 7;               // 0..7 (8 lcols each)
    int gcb    = (col8 >> 2)*64 + (col8 & 3)*8;

    #pragma unroll
    for (int p=0; p<2; ++p){
        if (p) __syncthreads();
        #pragma unroll
        for (int nj=0; nj<2; ++nj){
            int ni = p*2 + nj;
            int lcol = wn*32 + nj*16 + lm;
            #pragma unroll
            for (int mi=0; mi<4; ++mi){
                #pragma unroll
                for (int t2=0; t2<4; ++t2){
                    int lr = wm*64 + mi*16 + quad*4 + t2;
                    Cs[lr*66 + lcol] = (acc[mi][ni][t2] + bvv[ni]) * scv[ni];
                }
            }
        }
        __syncthreads();
        int cw = cbase + gcb + p*32;
        #pragma unroll
        for (int it=0; it<4; ++it){
            int rl = rowl_s + it*32;
            int r = row0 + rl;
            if (r < NN){
                const float* src = &Cs[rl*66 + col8*8];
                float cf[8];
                *(float4*)&cf[0] = *(const float4*)&src[0];
                *(float4*)&cf[4] = *(const float4*)&src[4];
                if (bufi == 0){
                    uint4 o;
                    o.x = (unsigned)f2bf(cf[0]) | ((unsigned)f2bf(cf[1])<<16);
                    o.y = (unsigned)f2bf(cf[2]) | ((unsigned)f2bf(cf[3])<<16);
                    o.z = (unsigned)f2bf(cf[4]) | ((unsigned)f2bf(cf[5])<<16);
                    o.w = (unsigned)f2bf(cf[6]) | ((unsigned)f2bf(cf[7])<<16);
                    *(uint4*)&qb[(size_t)r*256 + cw] = o;
                } else if (bufi <= 2){
                    int rel = bufi - 1;
                    uint2 o = enc8_fp8(cf);
                    *(uint2*)&kvb[(size_t)(rel*NN + r)*KVSTRIDE + cw] = o;
                } else {
                    int rel = bufi - 3;
                    uint2 o = enc8_fp8(cf);
                    *(uint2*)&kvb[(size_t)(rel*NN + r)*KVSTRIDE + 256 + cw] = o;
                }
            }
        }
    }
}

// ======================= K2: split-wave CSR attention, online softmax ==============
// kv row: kr fp8 (prel-scaled) + vr fp8 -> 512 B/edge gathered.
// A2 output in k-panel layout (A operand of gemmOln/gemmO)
__global__ __launch_bounds__(256) void attn_k(const u16* __restrict__ qb,
        const u8* __restrict__ kvb,
        const int* __restrict__ row_ptr, const int* __restrict__ epk,
        u16* __restrict__ A2){
    int wv = threadIdx.x >> 6, lane = threadIdx.x & 63;
    int node = blockIdx.x*4 + wv;
    int l32 = lane & 31;
    int half = lane >> 5;
    int start = row_ptr[node], end = row_ptr[node+1];
    float qf[8];
    {
        uint4 qr = *(const uint4*)&qb[(size_t)node*256 + l32*8];
        dec8(qr, qf);
    }
    float m = -1e30f, s = 0.f;
    float acc[8] = {0.f,0.f,0.f,0.f,0.f,0.f,0.f,0.f};

    int i0 = start + half;
    uint2 k0={0,0}, k1={0,0}, v0={0,0}, v1={0,0};
    if (i0 < end){
        const u8* row = &kvb[(size_t)epk[i0]*KVSTRIDE];
        k0 = *(const uint2*)(row + l32*8);
        v0 = *(const uint2*)(row + 256 + l32*8);
    }
    if (i0 + 2 < end){
        const u8* row = &kvb[(size_t)epk[i0+2]*KVSTRIDE];
        k1 = *(const uint2*)(row + l32*8);
        v1 = *(const uint2*)(row + 256 + l32*8);
    }
    int pk = (i0 + 4 < end) ? epk[i0+4] : 0;

    for (int i = i0; i < end; i += 2){
        uint2 kc = k0, vc = v0;
        k0 = k1; v0 = v1;
        if (i + 4 < end){                      // refill depth-2 slot
            const u8* row = &kvb[(size_t)pk*KVSTRIDE];
            k1 = *(const uint2*)(row + l32*8);
            v1 = *(const uint2*)(row + 256 + l32*8);
        }
        if (i + 6 < end) pk = epk[i+6];        // index 3 deep
        float kv[8];
        dec8_fp8(kc, kv);
        float p = dot8(qf, kv);
        p += __shfl_xor(p, 1);
        p += __shfl_xor(p, 2);                 // logit (prel/sqrt folded into kr)
        float mo = m;
        m = fmaxf(m, p);
        float sc = __expf(mo - m);
        float pe = __expf(p - m);
        s = s*sc + pe;
        float vv[8];
        dec8_fp8(vc, vv);
        #pragma unroll
        for (int j=0;j<8;++j) acc[j] = acc[j]*sc + pe*vv[j];
    }
    // merge the two halves' online-softmax states (m=-1e30: no inf-inf NaN)
    float mO = __shfl_xor(m, 32);
    float mA = fmaxf(m, mO);
    float eS = __expf(m - mA);
    float sh = s * eS;
    float sA = sh + __shfl_xor(sh, 32);
    float rs = 1.f / fmaxf(sA, 1e-16f);
    float oA[8];
    #pragma unroll
    for (int j=0;j<8;++j){
        float a = acc[j] * eS;
        oA[j] = a + __shfl_xor(a, 32);
    }
    if (half == 0){
        u16 o[8];
        #pragma unroll
        for (int j=0;j<8;++j) o[j] = f2bf(gelu_exact(oA[j]*rs));
        uint4 ov;
        ov.x = (unsigned)o[0] | ((unsigned)o[1]<<16);
        ov.y = (unsigned)o[2] | ((unsigned)o[3]<<16);
        ov.z = (unsigned)o[4] | ((unsigned)o[5]<<16);
        ov.w = (unsigned)o[6] | ((unsigned)o[7]<<16);
        int c0 = l32*8;
        *(uint4*)&A2[(size_t)(c0>>5)*APAN + (size_t)node*32 + (c0&31)] = ov;
    }
}

// ======================= K3a: out GEMM + skip + relu + LN (layers 0-2) ===========
// A2 and Wto in k-panel layout -> contiguous staging runs.
// emits h_out fp32 (row-major) and hbf bf16 k-panels for next gemm5
__global__ __launch_bounds__(256) void gemmOln_k(const u16* __restrict__ A,
        const u16* __restrict__ Wt, const float* __restrict__ bias,
        const float* __restrict__ h_in, const float* __restrict__ skip_l,
        const float* __restrict__ g, const float* __restrict__ b,
        float* __restrict__ h_out, u16* __restrict__ hbf){
    __shared__ u16 As[2048];          // 64 rows x 32 k
    __shared__ u16 Bs[8192];          // 256 cols x 32 k
    __shared__ float part_s[64*33];
    __shared__ float part_q[64*33];
    __shared__ float mu_s[64], rstd_s[64];
    int tid = threadIdx.x;
    int w = tid >> 6, lane = tid & 63;
    int row0 = blockIdx.x * 64;
    int wm = w & 1, wn = w >> 1;
    f32x4 acc[2][8];
    #pragma unroll
    for (int i=0;i<2;++i)
        #pragma unroll
        for (int j=0;j<8;++j) acc[i][j] = (f32x4){0.f,0.f,0.f,0.f};

    int lm = lane & 15, quad = lane >> 4;
    int kq0 = quad ^ (lm & 3);
    int aoff = (wm*32 + lm)*32 + kq0*8;
    int boff = (wn*128 + lm)*32 + kq0*8;

    for (int kk = 0; kk < 8; ++kk){
        {
            int s = tid;                       // 256 slots = 64 rows x 4
            int row = s >> 2, q0 = s & 3;
            int kq = q0 ^ (row & 3);
            gload_lds16(&A[(size_t)kk*APAN + (size_t)(row0+row)*32 + kq*8], &As[(size_t)(w*64)*8]);
        }
        #pragma unroll
        for (int it = 0; it < 4; ++it){        // 1024 slots = 256 n-rows x 4
            int s = it*256 + w*64 + lane;
            int row = s >> 2, q0 = s & 3;
            int kq = q0 ^ (row & 3);
            gload_lds16(&Wt[(size_t)kk*OPAN + (size_t)row*32 + kq*8], &Bs[(size_t)(it*256 + w*64)*8]);
        }
        __syncthreads();
        bf16x8 af[2], bfr[8];
        #pragma unroll
        for (int mi=0; mi<2; ++mi) af[mi]  = *(bf16x8*)&As[aoff + mi*512];
        #pragma unroll
        for (int ni=0; ni<8; ++ni) bfr[ni] = *(bf16x8*)&Bs[boff + ni*512];
        #pragma unroll
        for (int mi=0; mi<2; ++mi)
            #pragma unroll
            for (int ni=0; ni<8; ++ni)
                acc[mi][ni] = __builtin_amdgcn_mfma_f32_16x16x32_bf16(af[mi], bfr[ni], acc[mi][ni], 0,0,0);
        __syncthreads();
    }

    float sskip = 1.f/(1.f+__expf(-skip_l[0]));
    float osk = 1.f - sskip;
    float bv[8], gv[8], bbv[8];
    #pragma unroll
    for (int ni=0; ni<8; ++ni){
        int colg = wn*128 + ni*16 + lm;
        bv[ni]  = bias[colg];
        gv[ni]  = g[colg];
        bbv[ni] = b[colg];
    }
    #pragma unroll
    for (int mi=0; mi<2; ++mi){
        #pragma unroll
        for (int t=0; t<4; ++t){
            int lr = wm*32 + mi*16 + quad*4 + t;
            int r = row0 + lr;
            float ps = 0.f, pq = 0.f;
            #pragma unroll
            for (int ni=0; ni<8; ++ni){
                int colg = wn*128 + ni*16 + lm;
                float hv = (r < NN) ? h_in[(size_t)r*256 + colg] : 0.f;
                float val = sskip*(acc[mi][ni][t] + bv[ni]) + osk*hv;
                val = fmaxf(val, 0.f);
                acc[mi][ni][t] = val;
                ps += val; pq += val*val;
            }
            part_s[lr*33 + wn*16 + lm] = ps;
            part_q[lr*33 + wn*16 + lm] = pq;
        }
    }
    __syncthreads();
    if (tid < 64){
        float S = 0.f, Q = 0.f;
        #pragma unroll 8
        for (int t2=0; t2<32; ++t2){
            S += part_s[tid*33 + t2];
            Q += part_q[tid*33 + t2];
        }
        float mu = S * (1.f/256.f);
        float var = Q * (1.f/256.f) - mu*mu;
        mu_s[tid] = mu;
        rstd_s[tid] = rsqrtf(var + 1e-5f);
    }
    __syncthreads();
    #pragma unroll
    for (int mi=0; mi<2; ++mi){
        #pragma unroll
        for (int t=0; t<4; ++t){
            int lr = wm*32 + mi*16 + quad*4 + t;
            int r = row0 + lr;
            if (r >= NN) continue;
            float mu = mu_s[lr], rstd = rstd_s[lr];
            #pragma unroll
            for (int ni=0; ni<8; ++ni){
                int colg = wn*128 + ni*16 + lm;
                float o = (acc[mi][ni][t] - mu)*rstd*gv[ni] + bbv[ni];
                h_out[(size_t)r*256 + colg] = o;
                hbf[(size_t)(colg>>5)*APAN + (size_t)r*32 + (colg&31)] = f2bf(o);
            }
        }
    }
}

// ======================= K3b: out GEMM + skip blend (final layer) =======================
// A2 and Wto in k-panel layout
__global__ __launch_bounds__(256) void gemmO_k(const u16* __restrict__ A,
        const u16* __restrict__ Wt, const float* __restrict__ bias,
        const float* __restrict__ h_in, const float* __restrict__ skip_l,
        float* __restrict__ outp){
    __shared__ u16 As[4096];
    __shared__ u16 Bs[4096];
    int tid = threadIdx.x;
    int w = tid >> 6, lane = tid & 63;
    int row0 = blockIdx.x * 128;
    int col0 = blockIdx.y * 128;
    int wm = w & 1, wn = w >> 1;
    f32x4 acc[4][4];
    #pragma unroll
    for (int i=0;i<4;++i)
        #pragma unroll
        for (int j=0;j<4;++j) acc[i][j] = (f32x4){0.f,0.f,0.f,0.f};

    int lm = lane & 15, quad = lane >> 4;
    int kq0 = quad ^ (lm & 3);
    int aoff = (wm*64 + lm)*32 + kq0*8;
    int boff = (wn*64 + lm)*32 + kq0*8;

    for (int kk = 0; kk < 8; ++kk){
        #pragma unroll
        for (int it = 0; it < 2; ++it){
            int s = w*128 + it*64 + lane;
            int row = s >> 2, q0 = s & 3;
            int kq = q0 ^ (row & 3);
            gload_lds16(&A [(size_t)kk*APAN + (size_t)(row0+row)*32 + kq*8], &As[(size_t)(w*128 + it*64)*8]);
            gload_lds16(&Wt[(size_t)kk*OPAN + (size_t)(col0+row)*32 + kq*8], &Bs[(size_t)(w*128 + it*64)*8]);
        }
        __syncthreads();
        bf16x8 af[4], bfr[4];
        #pragma unroll
        for (int mi=0; mi<4; ++mi) af[mi]  = *(bf16x8*)&As[aoff + mi*512];
        #pragma unroll
        for (int ni=0; ni<4; ++ni) bfr[ni] = *(bf16x8*)&Bs[boff + ni*512];
        #pragma unroll
        for (int mi=0; mi<4; ++mi)
            #pragma unroll
            for (int ni=0; ni<4; ++ni)
                acc[mi][ni] = __builtin_amdgcn_mfma_f32_16x16x32_bf16(af[mi], bfr[ni], acc[mi][ni], 0,0,0);
        __syncthreads();
    }
    float s = 1.f/(1.f+expf(-skip_l[0]));
    float os = 1.f - s;
    #pragma unroll
    for (int ni=0; ni<4; ++ni){
        int colg = col0 + wn*64 + ni*16 + lm;
        float bv = bias[colg];
        #pragma unroll
        for (int mi=0; mi<4; ++mi){
            #pragma unroll
            for (int t=0; t<4; ++t){
                int r = row0 + wm*64 + mi*16 + quad*4 + t;
                if (r < NN)
                    outp[(size_t)r*256 + colg] =
                        s*(acc[mi][ni][t] + bv) + os*h_in[(size_t)r*256 + colg];
            }
        }
    }
}

// ======================= host =======================
extern "C" void kernel_launch(void* const* d_in, const int* in_sizes, int n_in,
                              void* d_out, int out_size, void* d_ws, size_t ws_size,
                              hipStream_t stream){
    (void)in_sizes; (void)n_in; (void)out_size; (void)ws_size;
    const float* x     = (const float*)d_in[0];
    const int*   ei0   = (const int*)d_in[1];
    const int*   ei1   = (const int*)d_in[2];
    const float* kqv_w = (const float*)d_in[3];
    const float* kqv_b = (const float*)d_in[4];
    const float* out_w = (const float*)d_in[5];
    const float* out_b = (const float*)d_in[6];
    const float* skip  = (const float*)d_in[7];
    const float* krel  = (const float*)d_in[8];
    const float* vrel  = (const float*)d_in[9];
    const float* prel  = (const float*)d_in[10];
    const float* ln_g  = (const float*)d_in[11];
    const float* ln_b  = (const float*)d_in[12];
    float* outp = (float*)d_out;

    char* wp = (char*)d_ws;
    auto alloc = [&](size_t bytes)->void*{
        void* p = wp; wp += (bytes + 255) & ~(size_t)255; return p;
    };
    float* hA    = (float*)alloc((size_t)NN*CC*4);
    float* hB    = (float*)alloc((size_t)NN*CC*4);
    u16*   xbf   = (u16*)alloc((size_t)NPAD*CC*2);   // k-panel layout
    u16*   hbf   = (u16*)alloc((size_t)NPAD*CC*2);   // k-panel layout
    u16*   A2    = (u16*)alloc((size_t)NPAD*CC*2);   // k-panel layout
    u16*   qb    = (u16*)alloc((size_t)NN*CC*2);
    u8*    kvb   = (u8*)alloc((size_t)2*NN*KVSTRIDE);   // [rel*NN+node][kr fp8 || vr fp8]
    u16*   Wt5   = (u16*)alloc((size_t)4*1280*256*2);   // k-panel layout
    u16*   Wto   = (u16*)alloc((size_t)4*256*256*2);    // k-panel layout
    float* bias5 = (float*)alloc((size_t)4*1280*4);
    float* sc5   = (float*)alloc((size_t)4*1280*4);
    int* cnt     = (int*)alloc((size_t)NN*4);      // cnt+cursor adjacent: one memset
    int* cursor  = (int*)alloc((size_t)NN*4);
    int* incl    = (int*)alloc((size_t)NN*4);
    int* row_ptr = (int*)alloc((size_t)(NN+1)*4);
    int* bsum    = (int*)alloc(128*4);
    int* epk     = (int*)alloc((size_t)TE*4);

    // fused prep (weights + input cast) — one dispatch
    prep_k<<<8664,256,0,stream>>>(kqv_w, kqv_b, krel, vrel, prel, out_w, x,
                                  Wt5, xbf, Wto, bias5, sc5);

    // CSR build
    size_t cntBlk = ((size_t)NN*4 + 255) & ~(size_t)255;
    hipMemsetAsync(cnt, 0, cntBlk + (size_t)NN*4, stream);   // zero cnt AND cursor
    hist_k<<<1250,256,0,stream>>>(ei0, ei1, cnt);
    scan_block_k<<<79,256,0,stream>>>(cnt, incl, bsum);
    scan_bsum_k<<<1,128,0,stream>>>(bsum, 79);
    finalize_rowptr_k<<<79,256,0,stream>>>(cnt, incl, bsum, row_ptr);
    scatter_k<<<1250,256,0,stream>>>(ei0, ei1, row_ptr, cursor, epk);

    const float* h_in = x;
    const u16*   Ain  = xbf;
    float* houts[4] = {hA, hB, hA, outp};
    for (int l=0; l<4; ++l){
        gemm5_k<<<1600,256,0,stream>>>(Ain, Wt5 + (size_t)l*327680,
                bias5 + l*1280, sc5 + l*1280, qb, kvb);
        attn_k<<<5000,256,0,stream>>>(qb, kvb, row_ptr, epk, A2);
        if (l < 3){
            gemmOln_k<<<314,256,0,stream>>>(A2, Wto + (size_t)l*65536,
                    out_b + l*256, h_in, skip + l, ln_g + l*256, ln_b + l*256,
                    houts[l], hbf);
        } else {
            gemmO_k<<<dim3(157,2),256,0,stream>>>(A2, Wto + (size_t)l*65536,
                    out_b + l*256, h_in, skip + l, outp);
        }
        h_in = houts[l];
        Ain = hbf;
    }
}